// Round 11
// baseline (225.742 us; speedup 1.0000x reference)
//
#include <hip/hip_runtime.h>
#include <hip/hip_bf16.h>
#include <math.h>

#define B_    4
#define C_    128
#define H_    96
#define W_    96
#define HW_   9216          // H*W
#define NPIX  36864         // B*HW
#define BHWC  4718592       // B*HW*C
#define BATCH_STRIDE 1179648 // HW*C

typedef __attribute__((ext_vector_type(8))) short bfrag8;
typedef __attribute__((ext_vector_type(4))) float f32x4;

static __device__ __forceinline__ short f2bf(float f) {
  __hip_bfloat16 h = __float2bfloat16(f);
  short s;
  __builtin_memcpy(&s, &h, 2);
  return s;
}
static __device__ __forceinline__ float bf2f(short s) {
  unsigned u = ((unsigned)(unsigned short)s) << 16;
  float f;
  __builtin_memcpy(&f, &u, 4);
  return f;
}

// ---------------- weight transposes ----------------
// wtb: bf16 A-frag order [k][mt(8)][kk(4)][lane(64)][j(8)] for de_w (147456)
// wob: bf16 A-frag order [k][mt(2)][kk(4)][lane(64)][j(8)] for off_w (36864)
// pwt: [c][oc] from pw_w [oc][c] (16384)
__global__ void k_transpose_w(const float* __restrict__ de_w,
                              const float* __restrict__ off_w,
                              const float* __restrict__ pw_w,
                              short* __restrict__ wtb, short* __restrict__ wob,
                              float* __restrict__ pwt) {
  int i = blockIdx.x * 256 + threadIdx.x;
  if (i < 147456) {
    int j  = i & 7;
    int l  = (i >> 3) & 63;
    int kk = (i >> 9) & 3;
    int mt = (i >> 11) & 7;
    int k  = i >> 14;
    int oc = mt * 16 + (l & 15);
    int c  = kk * 32 + ((l >> 4) << 3) + j;
    wtb[i] = f2bf(de_w[(oc * 128 + c) * 9 + k]);
  }
  if (i < 36864) {
    int j  = i & 7;
    int l  = (i >> 3) & 63;
    int kk = (i >> 9) & 3;
    int mt = (i >> 11) & 1;
    int k  = i >> 12;
    int oc = mt * 16 + (l & 15);
    int c  = kk * 32 + ((l >> 4) << 3) + j;
    wob[i] = (oc < 18) ? f2bf(off_w[(oc * 128 + c) * 9 + k]) : (short)0;
  }
  if (i < 16384) {
    int oc = i & 127; int c = i >> 7;
    pwt[i] = pw_w[oc * 128 + c];
  }
}

// ---------------- depthwise 3x3 + bias : NCHW in -> NCHW out ----------------
__global__ void k_dw(const float* __restrict__ x, const float* __restrict__ dw_w,
                     const float* __restrict__ dw_b, float* __restrict__ h1) {
  int i = blockIdx.x * 256 + threadIdx.x;
  if (i >= BHWC) return;
  int xx = i % 96; int yy = (i / 96) % 96; int c = (i / HW_) % 128; int b = i / BATCH_STRIDE;
  const float* xp = x + (b * 128 + c) * HW_;
  const float* wp = dw_w + c * 9;
  float acc = dw_b[c];
  #pragma unroll
  for (int dy = 0; dy < 3; ++dy) {
    int sy = yy + dy - 1;
    if (sy < 0 || sy >= 96) continue;
    #pragma unroll
    for (int dx = 0; dx < 3; ++dx) {
      int sx = xx + dx - 1;
      if (sx < 0 || sx >= 96) continue;
      acc += xp[sy * 96 + sx] * wp[dy * 3 + dx];
    }
  }
  h1[i] = acc;
}

// ---------------- pointwise 1x1 + bias : NCHW in -> BHWC out ----------------
__global__ __launch_bounds__(256) void k_pw(
    const float* __restrict__ h1, const float* __restrict__ pwt,
    const float* __restrict__ pw_b, float* __restrict__ s) {
  __shared__ float samp[32 * 128];
  int tid = threadIdx.x;
  int pixbase = blockIdx.x * 32;
  int b = pixbase / HW_;
  int hw0 = pixbase % HW_;

  if (tid < 128) {
    const float* hp = h1 + (size_t)(b * 128 + tid) * HW_ + hw0;
    #pragma unroll
    for (int p4 = 0; p4 < 8; ++p4) {
      float4 v = *(const float4*)(hp + p4 * 4);
      *(float4*)&samp[p4 * 512 + tid * 4] = v;
    }
  }
  __syncthreads();

  int to = tid & 31;
  int tp = tid >> 5;
  float acc[4][4];
  #pragma unroll
  for (int i = 0; i < 4; ++i)
    #pragma unroll
    for (int j = 0; j < 4; ++j) acc[i][j] = 0.f;

  const float4* wp4 = (const float4*)pwt;
  const float4* sp4 = (const float4*)&samp[tp * 512];
  #pragma unroll 8
  for (int c = 0; c < 128; ++c) {
    float4 w4 = wp4[c * 32 + to];
    float4 s4 = sp4[c];
    float wr[4] = {w4.x, w4.y, w4.z, w4.w};
    float sr[4] = {s4.x, s4.y, s4.z, s4.w};
    #pragma unroll
    for (int i = 0; i < 4; ++i)
      #pragma unroll
      for (int j = 0; j < 4; ++j)
        acc[i][j] = fmaf(wr[i], sr[j], acc[i][j]);
  }

  float b0 = pw_b[4 * to + 0], b1 = pw_b[4 * to + 1],
        b2 = pw_b[4 * to + 2], b3 = pw_b[4 * to + 3];
  #pragma unroll
  for (int j = 0; j < 4; ++j) {
    int pix = pixbase + 4 * tp + j;
    float4 v = make_float4(acc[0][j] + b0, acc[1][j] + b1, acc[2][j] + b2, acc[3][j] + b3);
    *(float4*)(s + (size_t)pix * 128 + 4 * to) = v;
  }
}

// ---------------- InstanceNorm stats (per b,c over HW) ----------------
__global__ void k_instats(const float* __restrict__ s, float* __restrict__ ist) {
  int b = blockIdx.x / 36; int tile = blockIdx.x % 36;
  int c = threadIdx.x & 127; int half = threadIdx.x >> 7;
  const float* base = s + (size_t)(b * HW_ + tile * 256) * 128;
  float sum = 0.f, sq = 0.f;
  for (int p = half; p < 256; p += 2) {
    float v = base[p * 128 + c];
    sum += v; sq += v * v;
  }
  __shared__ float r1[256], r2[256];
  r1[threadIdx.x] = sum; r2[threadIdx.x] = sq;
  __syncthreads();
  if (half == 0) {
    atomicAdd(&ist[(b * 128 + c) * 2],     r1[c] + r1[c + 128]);
    atomicAdd(&ist[(b * 128 + c) * 2 + 1], r2[c] + r2[c + 128]);
  }
}

__global__ void k_infin(const float* __restrict__ ist, float* __restrict__ ifm,
                        float* __restrict__ ifr) {
  int i = blockIdx.x * 256 + threadIdx.x;
  if (i >= 512) return;
  float mean = ist[2 * i] * (1.f / 9216.f);
  float var  = ist[2 * i + 1] * (1.f / 9216.f) - mean * mean;
  ifm[i] = mean;
  ifr[i] = rsqrtf(var + 1e-5f);
}

// ---------------- normalize s -> bf16 pixel-major [pix][128] ---------------
__global__ __launch_bounds__(256) void k_norm(
    const float* __restrict__ s, const float* __restrict__ ifm,
    const float* __restrict__ ifr, short* __restrict__ nsamp) {
  int t = blockIdx.x * 256 + threadIdx.x;   // t < NPIX*16
  int pix = t >> 4; int c0 = (t & 15) * 8;
  int b = pix / HW_;
  const float* sp = s + (size_t)pix * 128 + c0;
  float4 a0 = *(const float4*)sp, a1 = *(const float4*)(sp + 4);
  float4 m0 = *(const float4*)(ifm + b * 128 + c0), m1 = *(const float4*)(ifm + b * 128 + c0 + 4);
  float4 r0 = *(const float4*)(ifr + b * 128 + c0), r1 = *(const float4*)(ifr + b * 128 + c0 + 4);
  bfrag8 o;
  o[0] = f2bf(fmaxf((a0.x - m0.x) * r0.x, 0.f));
  o[1] = f2bf(fmaxf((a0.y - m0.y) * r0.y, 0.f));
  o[2] = f2bf(fmaxf((a0.z - m0.z) * r0.z, 0.f));
  o[3] = f2bf(fmaxf((a0.w - m0.w) * r0.w, 0.f));
  o[4] = f2bf(fmaxf((a1.x - m1.x) * r1.x, 0.f));
  o[5] = f2bf(fmaxf((a1.y - m1.y) * r1.y, 0.f));
  o[6] = f2bf(fmaxf((a1.z - m1.z) * r1.z, 0.f));
  o[7] = f2bf(fmaxf((a1.w - m1.w) * r1.w, 0.f));
  *(bfrag8*)(nsamp + (size_t)pix * 128 + c0) = o;
}

// ---------------- offset conv as MFMA GEMM with shifted fragments ----------
// nsamp is pixel-major: frag element (q, kk, g) at bfrag8 index q*16 + kk*4 + g.
__global__ __launch_bounds__(256) void k_offgemm(
    const short* __restrict__ nsamp, const short* __restrict__ wob,
    const float* __restrict__ off_b, float* __restrict__ off) {
  int tid = threadIdx.x;
  int lane = tid & 63, wv = tid >> 6;
  int p0 = blockIdx.x * 128 + wv * 32;
  int lp = lane & 15, g = lane >> 4;
  const bfrag8* np = (const bfrag8*)nsamp;
  const bfrag8* wp = (const bfrag8*)wob;

  f32x4 acc[2][2];
  #pragma unroll
  for (int m = 0; m < 2; ++m)
    #pragma unroll
    for (int n = 0; n < 2; ++n) acc[m][n] = (f32x4){0.f, 0.f, 0.f, 0.f};

  int pn0 = p0 + lp, pn1 = p0 + 16 + lp;
  int x0_ = pn0 % 96, y0_ = (pn0 % HW_) / 96;
  int x1_ = pn1 % 96, y1_ = (pn1 % HW_) / 96;
  const bfrag8 zf = {0, 0, 0, 0, 0, 0, 0, 0};

  for (int k = 0; k < 9; ++k) {
    int dy = k / 3 - 1, dx = k % 3 - 1;
    int sh = dy * 96 + dx;
    bool v0 = ((unsigned)(x0_ + dx) < 96u) && ((unsigned)(y0_ + dy) < 96u);
    bool v1 = ((unsigned)(x1_ + dx) < 96u) && ((unsigned)(y1_ + dy) < 96u);
    int q0 = min(max(pn0 + sh, 0), NPIX - 1);
    int q1 = min(max(pn1 + sh, 0), NPIX - 1);
    size_t a0 = (size_t)q0 * 16 + g;
    size_t a1 = (size_t)q1 * 16 + g;
    #pragma unroll
    for (int kk = 0; kk < 4; ++kk) {
      bfrag8 B0 = np[a0 + kk * 4]; B0 = v0 ? B0 : zf;
      bfrag8 B1 = np[a1 + kk * 4]; B1 = v1 ? B1 : zf;
      bfrag8 A0 = wp[((size_t)(k * 2 + 0) * 4 + kk) * 64 + lane];
      bfrag8 A1 = wp[((size_t)(k * 2 + 1) * 4 + kk) * 64 + lane];
      acc[0][0] = __builtin_amdgcn_mfma_f32_16x16x32_bf16(A0, B0, acc[0][0], 0, 0, 0);
      acc[0][1] = __builtin_amdgcn_mfma_f32_16x16x32_bf16(A0, B1, acc[0][1], 0, 0, 0);
      acc[1][0] = __builtin_amdgcn_mfma_f32_16x16x32_bf16(A1, B0, acc[1][0], 0, 0, 0);
      acc[1][1] = __builtin_amdgcn_mfma_f32_16x16x32_bf16(A1, B1, acc[1][1], 0, 0, 0);
    }
  }

  #pragma unroll
  for (int mt = 0; mt < 2; ++mt) {
    #pragma unroll
    for (int r = 0; r < 4; ++r) {
      int oc = mt * 16 + g * 4 + r;
      if (oc < 18) {
        float bb = off_b[oc];
        off[(size_t)oc * NPIX + p0 + lp]      = acc[mt][0][r] + bb;
        off[(size_t)oc * NPIX + p0 + 16 + lp] = acc[mt][1][r] + bb;
      }
    }
  }
}

// ---------------- fused deform: sample->LDS (dbuf) + MFMA + GN stats --------
// block = 32 pix x 128 oc, 4 waves; grid 1152 (= 8*144, XCD-swizzled).
// Sampling: wave wv owns pixblk (wv&1) and kk-pair (wv>>1)*2; lane = (lp, g)
//   -> LDS writes lane-contiguous 1KB (zero bank conflicts), gathers 64B/pixel.
// MFMA: wave wv owns mt {wv*2, wv*2+1} x both pixblks (no A duplication).
__global__ __launch_bounds__(256) void k_deform_f(
    const short* __restrict__ nsamp, const float* __restrict__ off,
    const short* __restrict__ wtb, const float* __restrict__ de_b,
    float* __restrict__ d, float* __restrict__ gst) {
  __shared__ short lbuf[2][2][4][64][8];   // [buf][pb][kk][lane][j], 16 KB
  __shared__ float r1[256], r2[256];
  int tid = threadIdx.x;
  int bid = blockIdx.x;
  int wg = (bid & 7) * 144 + (bid >> 3);   // bijective for 1152
  int pixbase = wg * 32;

  int lane = tid & 63, wv = tid >> 6;
  int lp = lane & 15, g = lane >> 4;

  // sampling role
  int pb_s = wv & 1;
  int kk0  = (wv >> 1) * 2;
  int pix_s = pixbase + pb_s * 16 + lp;
  int hw_s = pix_s % HW_;
  int ys = hw_s / 96, xs = hw_s % 96;
  int qb = (pix_s / HW_) * HW_;
  const bfrag8* np = (const bfrag8*)nsamp;

  // mfma role
  int mtg0 = wv * 2;
  const bfrag8* wp = (const bfrag8*)wtb;

  f32x4 acc[2][2];
  #pragma unroll
  for (int m = 0; m < 2; ++m)
    #pragma unroll
    for (int n = 0; n < 2; ++n) acc[m][n] = (f32x4){0.f, 0.f, 0.f, 0.f};

  auto SAMPLE = [&](int k, int buf) {
    float dy = off[(size_t)(2 * k)     * NPIX + pix_s];
    float dx = off[(size_t)(2 * k + 1) * NPIX + pix_s];
    float py = (float)ys + (float)(k / 3 - 1) + dy;
    float px = (float)xs + (float)(k % 3 - 1) + dx;
    float y0f = floorf(py), x0f = floorf(px);
    float ly = py - y0f, lx = px - x0f;
    int y0 = (int)y0f, x0 = (int)x0f;
    bool vy0 = (y0 >= 0) && (y0 < 96), vy1 = (y0 + 1 >= 0) && (y0 + 1 < 96);
    bool vx0 = (x0 >= 0) && (x0 < 96), vx1 = (x0 + 1 >= 0) && (x0 + 1 < 96);
    float w00 = (vy0 && vx0) ? (1.f - ly) * (1.f - lx) : 0.f;
    float w01 = (vy0 && vx1) ? (1.f - ly) * lx : 0.f;
    float w10 = (vy1 && vx0) ? ly * (1.f - lx) : 0.f;
    float w11 = (vy1 && vx1) ? ly * lx : 0.f;
    int yc0 = min(max(y0, 0), 95), yc1 = min(max(y0 + 1, 0), 95);
    int xc0 = min(max(x0, 0), 95), xc1 = min(max(x0 + 1, 0), 95);
    size_t b00 = (size_t)(qb + yc0 * 96 + xc0) * 16 + g;
    size_t b01 = (size_t)(qb + yc0 * 96 + xc1) * 16 + g;
    size_t b10 = (size_t)(qb + yc1 * 96 + xc0) * 16 + g;
    size_t b11 = (size_t)(qb + yc1 * 96 + xc1) * 16 + g;
    #pragma unroll
    for (int t2 = 0; t2 < 2; ++t2) {
      int kk = kk0 + t2;
      bfrag8 cA = np[b00 + kk * 4];
      bfrag8 cB = np[b01 + kk * 4];
      bfrag8 cC = np[b10 + kk * 4];
      bfrag8 cD = np[b11 + kk * 4];
      bfrag8 o;
      #pragma unroll
      for (int j = 0; j < 8; ++j) {
        float v = bf2f(cA[j]) * w00 + bf2f(cB[j]) * w01
                + bf2f(cC[j]) * w10 + bf2f(cD[j]) * w11;
        o[j] = f2bf(v);
      }
      *(bfrag8*)&lbuf[buf][pb_s][kk][lane][0] = o;   // lane-contiguous: no conflicts
    }
  };

  SAMPLE(0, 0);
  __syncthreads();
  for (int k = 0; k < 9; ++k) {
    int cur = k & 1;
    if (k < 8) SAMPLE(k + 1, cur ^ 1);
    #pragma unroll
    for (int kk = 0; kk < 4; ++kk) {
      bfrag8 B0 = *(const bfrag8*)&lbuf[cur][0][kk][lane][0];
      bfrag8 B1 = *(const bfrag8*)&lbuf[cur][1][kk][lane][0];
      #pragma unroll
      for (int m = 0; m < 2; ++m) {
        bfrag8 af = wp[((size_t)((k * 8 + mtg0 + m) * 4 + kk)) * 64 + lane];
        acc[m][0] = __builtin_amdgcn_mfma_f32_16x16x32_bf16(af, B0, acc[m][0], 0, 0, 0);
        acc[m][1] = __builtin_amdgcn_mfma_f32_16x16x32_bf16(af, B1, acc[m][1], 0, 0, 0);
      }
    }
    __syncthreads();
  }

  // epilogue: bias + store + GN partials. D: lane l reg r -> oc_local=(l>>4)*4+r, pix=l&15
  float lsum = 0.f, lsq = 0.f;
  #pragma unroll
  for (int m = 0; m < 2; ++m) {
    int oc = (mtg0 + m) * 16 + g * 4;
    float4 bias = *(const float4*)(de_b + oc);
    #pragma unroll
    for (int n = 0; n < 2; ++n) {
      int pix = pixbase + n * 16 + lp;
      f32x4 a = acc[m][n];
      float4 v = make_float4(a[0] + bias.x, a[1] + bias.y, a[2] + bias.z, a[3] + bias.w);
      *(float4*)(d + (size_t)pix * 128 + oc) = v;
      lsum += v.x + v.y + v.z + v.w;
      lsq  += v.x * v.x + v.y * v.y + v.z * v.z + v.w * v.w;
    }
  }
  r1[tid] = lsum; r2[tid] = lsq;
  __syncthreads();
  for (int st = 128; st > 0; st >>= 1) {
    if (tid < st) { r1[tid] += r1[tid + st]; r2[tid] += r2[tid + st]; }
    __syncthreads();
  }
  if (tid == 0) {
    int b = pixbase / HW_;
    atomicAdd(&gst[b * 2],     r1[0]);
    atomicAdd(&gst[b * 2 + 1], r2[0]);
  }
}

__global__ void k_gnfin(const float* __restrict__ gst, float* __restrict__ gfin) {
  int b = threadIdx.x;
  if (b >= 4) return;
  const float invN = 1.f / (float)BATCH_STRIDE;
  float mean = gst[2 * b] * invN;
  float var  = gst[2 * b + 1] * invN - mean * mean;
  gfin[2 * b] = mean;
  gfin[2 * b + 1] = rsqrtf(var + 1e-5f);
}

// ---------------- final: GN + sigmoid gate + shortcut, LDS transpose --------
__global__ __launch_bounds__(256) void k_final(
    const float* __restrict__ d, const float* __restrict__ s,
    const float* __restrict__ ifm, const float* __restrict__ ifr,
    const float* __restrict__ gfin, const float* __restrict__ gn_w,
    const float* __restrict__ gn_b, float* __restrict__ out) {
  __shared__ float t[128 * 33];
  int tid = threadIdx.x;
  int pixbase = blockIdx.x * 32;
  int b = pixbase / HW_;
  int hw0 = pixbase % HW_;
  float gm = gfin[2 * b], gr = gfin[2 * b + 1];

  int px0 = tid >> 3;
  int c0  = (tid & 7) * 16;
  const float* dp = d + ((size_t)(pixbase + px0)) * 128;
  const float* sp = s + ((size_t)(pixbase + px0)) * 128;
  #pragma unroll
  for (int q = 0; q < 4; ++q) {
    int c = c0 + q * 4;
    float4 dv = *(const float4*)(dp + c);
    float4 sv = *(const float4*)(sp + c);
    float4 m4 = *(const float4*)(ifm + b * 128 + c);
    float4 r4 = *(const float4*)(ifr + b * 128 + c);
    float4 w4 = *(const float4*)(gn_w + c);
    float4 b4 = *(const float4*)(gn_b + c);
    float svn, dn, gg;
    svn = fmaxf((sv.x - m4.x) * r4.x, 0.f);
    dn  = (dv.x - gm) * gr * w4.x + b4.x;
    gg  = 1.f / (1.f + expf(-dn));
    t[(c + 0) * 33 + px0] = svn * (1.f + gg);
    svn = fmaxf((sv.y - m4.y) * r4.y, 0.f);
    dn  = (dv.y - gm) * gr * w4.y + b4.y;
    gg  = 1.f / (1.f + expf(-dn));
    t[(c + 1) * 33 + px0] = svn * (1.f + gg);
    svn = fmaxf((sv.z - m4.z) * r4.z, 0.f);
    dn  = (dv.z - gm) * gr * w4.z + b4.z;
    gg  = 1.f / (1.f + expf(-dn));
    t[(c + 2) * 33 + px0] = svn * (1.f + gg);
    svn = fmaxf((sv.w - m4.w) * r4.w, 0.f);
    dn  = (dv.w - gm) * gr * w4.w + b4.w;
    gg  = 1.f / (1.f + expf(-dn));
    t[(c + 3) * 33 + px0] = svn * (1.f + gg);
  }
  __syncthreads();
  if (tid < 128) {
    float* op = out + (size_t)(b * 128 + tid) * HW_ + hw0;
    #pragma unroll
    for (int p4 = 0; p4 < 8; ++p4) {
      float4 v = make_float4(t[tid * 33 + p4 * 4], t[tid * 33 + p4 * 4 + 1],
                             t[tid * 33 + p4 * 4 + 2], t[tid * 33 + p4 * 4 + 3]);
      *(float4*)(op + p4 * 4) = v;
    }
  }
}

extern "C" void kernel_launch(void* const* d_in, const int* in_sizes, int n_in,
                              void* d_out, int out_size, void* d_ws, size_t ws_size,
                              hipStream_t stream) {
  (void)in_sizes; (void)n_in; (void)out_size; (void)ws_size;
  const float* x     = (const float*)d_in[0];
  const float* dw_w  = (const float*)d_in[1];
  const float* dw_b  = (const float*)d_in[2];
  const float* pw_w  = (const float*)d_in[3];
  const float* pw_b  = (const float*)d_in[4];
  const float* off_w = (const float*)d_in[5];
  const float* off_b = (const float*)d_in[6];
  const float* de_w  = (const float*)d_in[7];
  const float* de_b  = (const float*)d_in[8];
  const float* gn_w  = (const float*)d_in[9];
  const float* gn_b  = (const float*)d_in[10];
  float* out = (float*)d_out;

  float* ws   = (float*)d_ws;
  float* h1   = ws;                 // NCHW depthwise out; reused as deform out d (BHWC)
  float* s    = h1 + BHWC;          // BHWC raw pw output (normalized on the fly)
  float* off  = s + BHWC;           // [18][NPIX] offsets (oc-major)
  short* wtb  = (short*)(off + NPIX * 18);  // bf16 A-frag de_w (147456 shorts)
  short* wob  = wtb + 147456;       // bf16 A-frag off_w (36864 shorts)
  float* pwt  = (float*)(wob + 36864);  // [c][oc] 16384
  float* ist  = pwt + 16384;        // [B][C][2] sum,sumsq
  float* ifm  = ist + 1024;         // [B][C] mean
  float* ifr  = ifm + 512;          // [B][C] rstd
  float* gst  = ifr + 512;          // [B][2]
  float* gfin = gst + 8;            // [B][2]
  short* nsamp = (short*)(gfin + 8);        // bf16 normalized s, pixel-major (NPIX*128)

  hipMemsetAsync(ist, 0, (1024 + 512 + 512 + 8 + 8) * sizeof(float), stream);

  k_transpose_w<<<576, 256, 0, stream>>>(de_w, off_w, pw_w, wtb, wob, pwt);
  k_dw<<<BHWC / 256, 256, 0, stream>>>(x, dw_w, dw_b, h1);
  k_pw<<<NPIX / 32, 256, 0, stream>>>(h1, pwt, pw_b, s);
  k_instats<<<4 * 36, 256, 0, stream>>>(s, ist);
  k_infin<<<2, 256, 0, stream>>>(ist, ifm, ifr);
  k_norm<<<NPIX * 16 / 256, 256, 0, stream>>>(s, ifm, ifr, nsamp);
  k_offgemm<<<NPIX / 128, 256, 0, stream>>>(nsamp, wob, off_b, off);
  k_deform_f<<<NPIX / 32, 256, 0, stream>>>(nsamp, off, wtb, de_b, h1, gst);
  k_gnfin<<<1, 64, 0, stream>>>(gst, gfin);
  k_final<<<NPIX / 32, 256, 0, stream>>>(h1, s, ifm, ifr, gfin, gn_w, gn_b, out);
}

// Round 12
// 217.332 us; speedup vs baseline: 1.0387x; 1.0387x over previous
//
#include <hip/hip_runtime.h>
#include <hip/hip_bf16.h>
#include <math.h>

#define B_    4
#define C_    128
#define H_    96
#define W_    96
#define HW_   9216          // H*W
#define NPIX  36864         // B*HW
#define BHWC  4718592       // B*HW*C
#define BATCH_STRIDE 1179648 // HW*C

typedef __attribute__((ext_vector_type(8))) short bfrag8;
typedef __attribute__((ext_vector_type(4))) float f32x4;

static __device__ __forceinline__ short f2bf(float f) {
  __hip_bfloat16 h = __float2bfloat16(f);
  short s;
  __builtin_memcpy(&s, &h, 2);
  return s;
}
static __device__ __forceinline__ float bf2f(short s) {
  unsigned u = ((unsigned)(unsigned short)s) << 16;
  float f;
  __builtin_memcpy(&f, &u, 4);
  return f;
}
// pack two f32 -> two bf16 (RNE) in one instruction
static __device__ __forceinline__ unsigned cvtpk(float lo, float hi) {
  unsigned r;
  asm("v_cvt_pk_bf16_f32 %0, %1, %2" : "=v"(r) : "v"(lo), "v"(hi));
  return r;
}

// ---------------- weight transposes ----------------
// wtb: bf16 A-frag order [k][mt(8)][kk(4)][lane(64)][j(8)] for de_w (147456)
// wob: bf16 A-frag order [k][mt(2)][kk(4)][lane(64)][j(8)] for off_w (36864)
// pwt: [c][oc] from pw_w [oc][c] (16384)
__global__ void k_transpose_w(const float* __restrict__ de_w,
                              const float* __restrict__ off_w,
                              const float* __restrict__ pw_w,
                              short* __restrict__ wtb, short* __restrict__ wob,
                              float* __restrict__ pwt) {
  int i = blockIdx.x * 256 + threadIdx.x;
  if (i < 147456) {
    int j  = i & 7;
    int l  = (i >> 3) & 63;
    int kk = (i >> 9) & 3;
    int mt = (i >> 11) & 7;
    int k  = i >> 14;
    int oc = mt * 16 + (l & 15);
    int c  = kk * 32 + ((l >> 4) << 3) + j;
    wtb[i] = f2bf(de_w[(oc * 128 + c) * 9 + k]);
  }
  if (i < 36864) {
    int j  = i & 7;
    int l  = (i >> 3) & 63;
    int kk = (i >> 9) & 3;
    int mt = (i >> 11) & 1;
    int k  = i >> 12;
    int oc = mt * 16 + (l & 15);
    int c  = kk * 32 + ((l >> 4) << 3) + j;
    wob[i] = (oc < 18) ? f2bf(off_w[(oc * 128 + c) * 9 + k]) : (short)0;
  }
  if (i < 16384) {
    int oc = i & 127; int c = i >> 7;
    pwt[i] = pw_w[oc * 128 + c];
  }
}

// ---------------- depthwise 3x3 + bias : NCHW in -> NCHW out ----------------
__global__ void k_dw(const float* __restrict__ x, const float* __restrict__ dw_w,
                     const float* __restrict__ dw_b, float* __restrict__ h1) {
  int i = blockIdx.x * 256 + threadIdx.x;
  if (i >= BHWC) return;
  int xx = i % 96; int yy = (i / 96) % 96; int c = (i / HW_) % 128; int b = i / BATCH_STRIDE;
  const float* xp = x + (b * 128 + c) * HW_;
  const float* wp = dw_w + c * 9;
  float acc = dw_b[c];
  #pragma unroll
  for (int dy = 0; dy < 3; ++dy) {
    int sy = yy + dy - 1;
    if (sy < 0 || sy >= 96) continue;
    #pragma unroll
    for (int dx = 0; dx < 3; ++dx) {
      int sx = xx + dx - 1;
      if (sx < 0 || sx >= 96) continue;
      acc += xp[sy * 96 + sx] * wp[dy * 3 + dx];
    }
  }
  h1[i] = acc;
}

// ---------------- pointwise 1x1 + bias : NCHW in -> BHWC out ----------------
__global__ __launch_bounds__(256) void k_pw(
    const float* __restrict__ h1, const float* __restrict__ pwt,
    const float* __restrict__ pw_b, float* __restrict__ s) {
  __shared__ float samp[32 * 128];
  int tid = threadIdx.x;
  int pixbase = blockIdx.x * 32;
  int b = pixbase / HW_;
  int hw0 = pixbase % HW_;

  if (tid < 128) {
    const float* hp = h1 + (size_t)(b * 128 + tid) * HW_ + hw0;
    #pragma unroll
    for (int p4 = 0; p4 < 8; ++p4) {
      float4 v = *(const float4*)(hp + p4 * 4);
      *(float4*)&samp[p4 * 512 + tid * 4] = v;
    }
  }
  __syncthreads();

  int to = tid & 31;
  int tp = tid >> 5;
  float acc[4][4];
  #pragma unroll
  for (int i = 0; i < 4; ++i)
    #pragma unroll
    for (int j = 0; j < 4; ++j) acc[i][j] = 0.f;

  const float4* wp4 = (const float4*)pwt;
  const float4* sp4 = (const float4*)&samp[tp * 512];
  #pragma unroll 8
  for (int c = 0; c < 128; ++c) {
    float4 w4 = wp4[c * 32 + to];
    float4 s4 = sp4[c];
    float wr[4] = {w4.x, w4.y, w4.z, w4.w};
    float sr[4] = {s4.x, s4.y, s4.z, s4.w};
    #pragma unroll
    for (int i = 0; i < 4; ++i)
      #pragma unroll
      for (int j = 0; j < 4; ++j)
        acc[i][j] = fmaf(wr[i], sr[j], acc[i][j]);
  }

  float b0 = pw_b[4 * to + 0], b1 = pw_b[4 * to + 1],
        b2 = pw_b[4 * to + 2], b3 = pw_b[4 * to + 3];
  #pragma unroll
  for (int j = 0; j < 4; ++j) {
    int pix = pixbase + 4 * tp + j;
    float4 v = make_float4(acc[0][j] + b0, acc[1][j] + b1, acc[2][j] + b2, acc[3][j] + b3);
    *(float4*)(s + (size_t)pix * 128 + 4 * to) = v;
  }
}

// ---------------- InstanceNorm stats (per b,c over HW) ----------------
__global__ void k_instats(const float* __restrict__ s, float* __restrict__ ist) {
  int b = blockIdx.x / 36; int tile = blockIdx.x % 36;
  int c = threadIdx.x & 127; int half = threadIdx.x >> 7;
  const float* base = s + (size_t)(b * HW_ + tile * 256) * 128;
  float sum = 0.f, sq = 0.f;
  for (int p = half; p < 256; p += 2) {
    float v = base[p * 128 + c];
    sum += v; sq += v * v;
  }
  __shared__ float r1[256], r2[256];
  r1[threadIdx.x] = sum; r2[threadIdx.x] = sq;
  __syncthreads();
  if (half == 0) {
    atomicAdd(&ist[(b * 128 + c) * 2],     r1[c] + r1[c + 128]);
    atomicAdd(&ist[(b * 128 + c) * 2 + 1], r2[c] + r2[c + 128]);
  }
}

__global__ void k_infin(const float* __restrict__ ist, float* __restrict__ ifm,
                        float* __restrict__ ifr) {
  int i = blockIdx.x * 256 + threadIdx.x;
  if (i >= 512) return;
  float mean = ist[2 * i] * (1.f / 9216.f);
  float var  = ist[2 * i + 1] * (1.f / 9216.f) - mean * mean;
  ifm[i] = mean;
  ifr[i] = rsqrtf(var + 1e-5f);
}

// ---------------- normalize s -> bf16 pixel-major [pix][128] ---------------
__global__ __launch_bounds__(256) void k_norm(
    const float* __restrict__ s, const float* __restrict__ ifm,
    const float* __restrict__ ifr, short* __restrict__ nsamp) {
  int t = blockIdx.x * 256 + threadIdx.x;   // t < NPIX*16
  int pix = t >> 4; int c0 = (t & 15) * 8;
  int b = pix / HW_;
  const float* sp = s + (size_t)pix * 128 + c0;
  float4 a0 = *(const float4*)sp, a1 = *(const float4*)(sp + 4);
  float4 m0 = *(const float4*)(ifm + b * 128 + c0), m1 = *(const float4*)(ifm + b * 128 + c0 + 4);
  float4 r0 = *(const float4*)(ifr + b * 128 + c0), r1 = *(const float4*)(ifr + b * 128 + c0 + 4);
  bfrag8 o;
  o[0] = f2bf(fmaxf((a0.x - m0.x) * r0.x, 0.f));
  o[1] = f2bf(fmaxf((a0.y - m0.y) * r0.y, 0.f));
  o[2] = f2bf(fmaxf((a0.z - m0.z) * r0.z, 0.f));
  o[3] = f2bf(fmaxf((a0.w - m0.w) * r0.w, 0.f));
  o[4] = f2bf(fmaxf((a1.x - m1.x) * r1.x, 0.f));
  o[5] = f2bf(fmaxf((a1.y - m1.y) * r1.y, 0.f));
  o[6] = f2bf(fmaxf((a1.z - m1.z) * r1.z, 0.f));
  o[7] = f2bf(fmaxf((a1.w - m1.w) * r1.w, 0.f));
  *(bfrag8*)(nsamp + (size_t)pix * 128 + c0) = o;
}

// ---------------- offset conv as MFMA GEMM with shifted fragments ----------
// nsamp is pixel-major: frag element (q, kk, g) at bfrag8 index q*16 + kk*4 + g.
__global__ __launch_bounds__(256) void k_offgemm(
    const short* __restrict__ nsamp, const short* __restrict__ wob,
    const float* __restrict__ off_b, float* __restrict__ off) {
  int tid = threadIdx.x;
  int lane = tid & 63, wv = tid >> 6;
  int p0 = blockIdx.x * 128 + wv * 32;
  int lp = lane & 15, g = lane >> 4;
  const bfrag8* np = (const bfrag8*)nsamp;
  const bfrag8* wp = (const bfrag8*)wob;

  f32x4 acc[2][2];
  #pragma unroll
  for (int m = 0; m < 2; ++m)
    #pragma unroll
    for (int n = 0; n < 2; ++n) acc[m][n] = (f32x4){0.f, 0.f, 0.f, 0.f};

  int pn0 = p0 + lp, pn1 = p0 + 16 + lp;
  int x0_ = pn0 % 96, y0_ = (pn0 % HW_) / 96;
  int x1_ = pn1 % 96, y1_ = (pn1 % HW_) / 96;
  const bfrag8 zf = {0, 0, 0, 0, 0, 0, 0, 0};

  for (int k = 0; k < 9; ++k) {
    int dy = k / 3 - 1, dx = k % 3 - 1;
    int sh = dy * 96 + dx;
    bool v0 = ((unsigned)(x0_ + dx) < 96u) && ((unsigned)(y0_ + dy) < 96u);
    bool v1 = ((unsigned)(x1_ + dx) < 96u) && ((unsigned)(y1_ + dy) < 96u);
    int q0 = min(max(pn0 + sh, 0), NPIX - 1);
    int q1 = min(max(pn1 + sh, 0), NPIX - 1);
    size_t a0 = (size_t)q0 * 16 + g;
    size_t a1 = (size_t)q1 * 16 + g;
    #pragma unroll
    for (int kk = 0; kk < 4; ++kk) {
      bfrag8 B0 = np[a0 + kk * 4]; B0 = v0 ? B0 : zf;
      bfrag8 B1 = np[a1 + kk * 4]; B1 = v1 ? B1 : zf;
      bfrag8 A0 = wp[((size_t)(k * 2 + 0) * 4 + kk) * 64 + lane];
      bfrag8 A1 = wp[((size_t)(k * 2 + 1) * 4 + kk) * 64 + lane];
      acc[0][0] = __builtin_amdgcn_mfma_f32_16x16x32_bf16(A0, B0, acc[0][0], 0, 0, 0);
      acc[0][1] = __builtin_amdgcn_mfma_f32_16x16x32_bf16(A0, B1, acc[0][1], 0, 0, 0);
      acc[1][0] = __builtin_amdgcn_mfma_f32_16x16x32_bf16(A1, B0, acc[1][0], 0, 0, 0);
      acc[1][1] = __builtin_amdgcn_mfma_f32_16x16x32_bf16(A1, B1, acc[1][1], 0, 0, 0);
    }
  }

  #pragma unroll
  for (int mt = 0; mt < 2; ++mt) {
    #pragma unroll
    for (int r = 0; r < 4; ++r) {
      int oc = mt * 16 + g * 4 + r;
      if (oc < 18) {
        float bb = off_b[oc];
        off[(size_t)oc * NPIX + p0 + lp]      = acc[mt][0][r] + bb;
        off[(size_t)oc * NPIX + p0 + 16 + lp] = acc[mt][1][r] + bb;
      }
    }
  }
}

// ---------------- fused deform: sample->LDS (dbuf) + MFMA + GN stats --------
// block = 32 pix x 128 oc, 4 waves; grid 1152 (= 8*144, XCD-swizzled).
// Sampling: lane = (pixel-in-quad lane>>4, 16B-chunk lane&15); each gather
//   instruction reads 4 pixels' FULL 256B corner rows -> 4 segments (was 16).
//   Lane blends its 8 channels locally; cvt_pk packs pairs in 1 instr.
// LDS lbuf[buf][pb][lp][17][8]: +1-chunk pad -> writes contiguous 256B runs
//   (conflict-free), B-frag reads 2-way (free).
// MFMA: wave wv owns mt {2wv, 2wv+1} x both pixblks.
__global__ __launch_bounds__(256) void k_deform_f(
    const short* __restrict__ nsamp, const float* __restrict__ off,
    const short* __restrict__ wtb, const float* __restrict__ de_b,
    float* __restrict__ d, float* __restrict__ gst) {
  __shared__ short lbuf[2][2][16][17][8];  // 17.4 KB
  __shared__ float r1[256], r2[256];
  int tid = threadIdx.x;
  int bid = blockIdx.x;
  int wg = (bid & 7) * 144 + (bid >> 3);   // bijective for 1152
  int pixbase = wg * 32;

  int lane = tid & 63, wv = tid >> 6;
  int lp = lane & 15, g = lane >> 4;

  // sampling role: lane = (pq = lane>>4, ch = lane&15)
  int pq = lane >> 4, ch = lane & 15;

  // mfma role
  int mtg0 = wv * 2;
  const bfrag8* wp = (const bfrag8*)wtb;

  f32x4 acc[2][2];
  #pragma unroll
  for (int m = 0; m < 2; ++m)
    #pragma unroll
    for (int n = 0; n < 2; ++n) acc[m][n] = (f32x4){0.f, 0.f, 0.f, 0.f};

  auto SAMPLE = [&](int k, int buf) {
    #pragma unroll
    for (int q = 0; q < 2; ++q) {
      int lpix = wv * 8 + q * 4 + pq;        // local pixel 0..31
      int pix  = pixbase + lpix;
      int hw = pix % HW_;
      int ys = hw / 96, xs = hw % 96;
      int qb = (pix / HW_) * HW_;
      float dy = off[(size_t)(2 * k)     * NPIX + pix];
      float dx = off[(size_t)(2 * k + 1) * NPIX + pix];
      float py = (float)ys + (float)(k / 3 - 1) + dy;
      float px = (float)xs + (float)(k % 3 - 1) + dx;
      float y0f = floorf(py), x0f = floorf(px);
      float ly = py - y0f, lx = px - x0f;
      int y0 = (int)y0f, x0 = (int)x0f;
      bool vy0 = (y0 >= 0) && (y0 < 96), vy1 = (y0 + 1 >= 0) && (y0 + 1 < 96);
      bool vx0 = (x0 >= 0) && (x0 < 96), vx1 = (x0 + 1 >= 0) && (x0 + 1 < 96);
      float w00 = (vy0 && vx0) ? (1.f - ly) * (1.f - lx) : 0.f;
      float w01 = (vy0 && vx1) ? (1.f - ly) * lx : 0.f;
      float w10 = (vy1 && vx0) ? ly * (1.f - lx) : 0.f;
      float w11 = (vy1 && vx1) ? ly * lx : 0.f;
      int yc0 = min(max(y0, 0), 95), yc1 = min(max(y0 + 1, 0), 95);
      int xc0 = min(max(x0, 0), 95), xc1 = min(max(x0 + 1, 0), 95);
      const short* base = nsamp + (size_t)ch * 8;
      bfrag8 cA = *(const bfrag8*)(base + (size_t)(qb + yc0 * 96 + xc0) * 128);
      bfrag8 cB = *(const bfrag8*)(base + (size_t)(qb + yc0 * 96 + xc1) * 128);
      bfrag8 cC = *(const bfrag8*)(base + (size_t)(qb + yc1 * 96 + xc0) * 128);
      bfrag8 cD = *(const bfrag8*)(base + (size_t)(qb + yc1 * 96 + xc1) * 128);
      float v[8];
      #pragma unroll
      for (int j = 0; j < 8; ++j) {
        v[j] = bf2f(cA[j]) * w00 + bf2f(cB[j]) * w01
             + bf2f(cC[j]) * w10 + bf2f(cD[j]) * w11;
      }
      unsigned o[4];
      o[0] = cvtpk(v[0], v[1]);
      o[1] = cvtpk(v[2], v[3]);
      o[2] = cvtpk(v[4], v[5]);
      o[3] = cvtpk(v[6], v[7]);
      *(uint4*)&lbuf[buf][lpix >> 4][lpix & 15][ch][0] =
          make_uint4(o[0], o[1], o[2], o[3]);
    }
  };

  SAMPLE(0, 0);
  __syncthreads();
  for (int k = 0; k < 9; ++k) {
    int cur = k & 1;
    if (k < 8) SAMPLE(k + 1, cur ^ 1);
    #pragma unroll
    for (int kk = 0; kk < 4; ++kk) {
      bfrag8 B0 = *(const bfrag8*)&lbuf[cur][0][lp][kk * 4 + g][0];
      bfrag8 B1 = *(const bfrag8*)&lbuf[cur][1][lp][kk * 4 + g][0];
      #pragma unroll
      for (int m = 0; m < 2; ++m) {
        bfrag8 af = wp[((size_t)((k * 8 + mtg0 + m) * 4 + kk)) * 64 + lane];
        acc[m][0] = __builtin_amdgcn_mfma_f32_16x16x32_bf16(af, B0, acc[m][0], 0, 0, 0);
        acc[m][1] = __builtin_amdgcn_mfma_f32_16x16x32_bf16(af, B1, acc[m][1], 0, 0, 0);
      }
    }
    __syncthreads();
  }

  // epilogue: bias + store + GN partials. D: lane l reg r -> oc_local=(l>>4)*4+r, pix=l&15
  float lsum = 0.f, lsq = 0.f;
  #pragma unroll
  for (int m = 0; m < 2; ++m) {
    int oc = (mtg0 + m) * 16 + g * 4;
    float4 bias = *(const float4*)(de_b + oc);
    #pragma unroll
    for (int n = 0; n < 2; ++n) {
      int pix = pixbase + n * 16 + lp;
      f32x4 a = acc[m][n];
      float4 v = make_float4(a[0] + bias.x, a[1] + bias.y, a[2] + bias.z, a[3] + bias.w);
      *(float4*)(d + (size_t)pix * 128 + oc) = v;
      lsum += v.x + v.y + v.z + v.w;
      lsq  += v.x * v.x + v.y * v.y + v.z * v.z + v.w * v.w;
    }
  }
  r1[tid] = lsum; r2[tid] = lsq;
  __syncthreads();
  for (int st = 128; st > 0; st >>= 1) {
    if (tid < st) { r1[tid] += r1[tid + st]; r2[tid] += r2[tid + st]; }
    __syncthreads();
  }
  if (tid == 0) {
    int b = pixbase / HW_;
    atomicAdd(&gst[b * 2],     r1[0]);
    atomicAdd(&gst[b * 2 + 1], r2[0]);
  }
}

__global__ void k_gnfin(const float* __restrict__ gst, float* __restrict__ gfin) {
  int b = threadIdx.x;
  if (b >= 4) return;
  const float invN = 1.f / (float)BATCH_STRIDE;
  float mean = gst[2 * b] * invN;
  float var  = gst[2 * b + 1] * invN - mean * mean;
  gfin[2 * b] = mean;
  gfin[2 * b + 1] = rsqrtf(var + 1e-5f);
}

// ---------------- final: GN + sigmoid gate + shortcut, LDS transpose --------
__global__ __launch_bounds__(256) void k_final(
    const float* __restrict__ d, const float* __restrict__ s,
    const float* __restrict__ ifm, const float* __restrict__ ifr,
    const float* __restrict__ gfin, const float* __restrict__ gn_w,
    const float* __restrict__ gn_b, float* __restrict__ out) {
  __shared__ float t[128 * 33];
  int tid = threadIdx.x;
  int pixbase = blockIdx.x * 32;
  int b = pixbase / HW_;
  int hw0 = pixbase % HW_;
  float gm = gfin[2 * b], gr = gfin[2 * b + 1];

  int px0 = tid >> 3;
  int c0  = (tid & 7) * 16;
  const float* dp = d + ((size_t)(pixbase + px0)) * 128;
  const float* sp = s + ((size_t)(pixbase + px0)) * 128;
  #pragma unroll
  for (int q = 0; q < 4; ++q) {
    int c = c0 + q * 4;
    float4 dv = *(const float4*)(dp + c);
    float4 sv = *(const float4*)(sp + c);
    float4 m4 = *(const float4*)(ifm + b * 128 + c);
    float4 r4 = *(const float4*)(ifr + b * 128 + c);
    float4 w4 = *(const float4*)(gn_w + c);
    float4 b4 = *(const float4*)(gn_b + c);
    float svn, dn, gg;
    svn = fmaxf((sv.x - m4.x) * r4.x, 0.f);
    dn  = (dv.x - gm) * gr * w4.x + b4.x;
    gg  = 1.f / (1.f + expf(-dn));
    t[(c + 0) * 33 + px0] = svn * (1.f + gg);
    svn = fmaxf((sv.y - m4.y) * r4.y, 0.f);
    dn  = (dv.y - gm) * gr * w4.y + b4.y;
    gg  = 1.f / (1.f + expf(-dn));
    t[(c + 1) * 33 + px0] = svn * (1.f + gg);
    svn = fmaxf((sv.z - m4.z) * r4.z, 0.f);
    dn  = (dv.z - gm) * gr * w4.z + b4.z;
    gg  = 1.f / (1.f + expf(-dn));
    t[(c + 2) * 33 + px0] = svn * (1.f + gg);
    svn = fmaxf((sv.w - m4.w) * r4.w, 0.f);
    dn  = (dv.w - gm) * gr * w4.w + b4.w;
    gg  = 1.f / (1.f + expf(-dn));
    t[(c + 3) * 33 + px0] = svn * (1.f + gg);
  }
  __syncthreads();
  if (tid < 128) {
    float* op = out + (size_t)(b * 128 + tid) * HW_ + hw0;
    #pragma unroll
    for (int p4 = 0; p4 < 8; ++p4) {
      float4 v = make_float4(t[tid * 33 + p4 * 4], t[tid * 33 + p4 * 4 + 1],
                             t[tid * 33 + p4 * 4 + 2], t[tid * 33 + p4 * 4 + 3]);
      *(float4*)(op + p4 * 4) = v;
    }
  }
}

extern "C" void kernel_launch(void* const* d_in, const int* in_sizes, int n_in,
                              void* d_out, int out_size, void* d_ws, size_t ws_size,
                              hipStream_t stream) {
  (void)in_sizes; (void)n_in; (void)out_size; (void)ws_size;
  const float* x     = (const float*)d_in[0];
  const float* dw_w  = (const float*)d_in[1];
  const float* dw_b  = (const float*)d_in[2];
  const float* pw_w  = (const float*)d_in[3];
  const float* pw_b  = (const float*)d_in[4];
  const float* off_w = (const float*)d_in[5];
  const float* off_b = (const float*)d_in[6];
  const float* de_w  = (const float*)d_in[7];
  const float* de_b  = (const float*)d_in[8];
  const float* gn_w  = (const float*)d_in[9];
  const float* gn_b  = (const float*)d_in[10];
  float* out = (float*)d_out;

  float* ws   = (float*)d_ws;
  float* h1   = ws;                 // NCHW depthwise out; reused as deform out d (BHWC)
  float* s    = h1 + BHWC;          // BHWC raw pw output (normalized on the fly)
  float* off  = s + BHWC;           // [18][NPIX] offsets (oc-major)
  short* wtb  = (short*)(off + NPIX * 18);  // bf16 A-frag de_w (147456 shorts)
  short* wob  = wtb + 147456;       // bf16 A-frag off_w (36864 shorts)
  float* pwt  = (float*)(wob + 36864);  // [c][oc] 16384
  float* ist  = pwt + 16384;        // [B][C][2] sum,sumsq
  float* ifm  = ist + 1024;         // [B][C] mean
  float* ifr  = ifm + 512;          // [B][C] rstd
  float* gst  = ifr + 512;          // [B][2]
  float* gfin = gst + 8;            // [B][2]
  short* nsamp = (short*)(gfin + 8);        // bf16 normalized s, pixel-major (NPIX*128)

  hipMemsetAsync(ist, 0, (1024 + 512 + 512 + 8 + 8) * sizeof(float), stream);

  k_transpose_w<<<576, 256, 0, stream>>>(de_w, off_w, pw_w, wtb, wob, pwt);
  k_dw<<<BHWC / 256, 256, 0, stream>>>(x, dw_w, dw_b, h1);
  k_pw<<<NPIX / 32, 256, 0, stream>>>(h1, pwt, pw_b, s);
  k_instats<<<4 * 36, 256, 0, stream>>>(s, ist);
  k_infin<<<2, 256, 0, stream>>>(ist, ifm, ifr);
  k_norm<<<NPIX * 16 / 256, 256, 0, stream>>>(s, ifm, ifr, nsamp);
  k_offgemm<<<NPIX / 128, 256, 0, stream>>>(nsamp, wob, off_b, off);
  k_deform_f<<<NPIX / 32, 256, 0, stream>>>(nsamp, off, wtb, de_b, h1, gst);
  k_gnfin<<<1, 64, 0, stream>>>(gst, gfin);
  k_final<<<NPIX / 32, 256, 0, stream>>>(h1, s, ifm, ifr, gfin, gn_w, gn_b, out);
}

// Round 13
// 202.434 us; speedup vs baseline: 1.1151x; 1.0736x over previous
//
#include <hip/hip_runtime.h>
#include <hip/hip_bf16.h>
#include <math.h>

#define B_    4
#define C_    128
#define H_    96
#define W_    96
#define HW_   9216          // H*W
#define NPIX  36864         // B*HW
#define BHWC  4718592       // B*HW*C
#define BATCH_STRIDE 1179648 // HW*C

typedef __attribute__((ext_vector_type(8))) short bfrag8;
typedef __attribute__((ext_vector_type(4))) float f32x4;

static __device__ __forceinline__ short f2bf(float f) {
  __hip_bfloat16 h = __float2bfloat16(f);
  short s;
  __builtin_memcpy(&s, &h, 2);
  return s;
}
static __device__ __forceinline__ float bf2f(short s) {
  unsigned u = ((unsigned)(unsigned short)s) << 16;
  float f;
  __builtin_memcpy(&f, &u, 4);
  return f;
}
// pack two f32 -> two bf16 (RNE) in one instruction
static __device__ __forceinline__ unsigned cvtpk(float lo, float hi) {
  unsigned r;
  asm("v_cvt_pk_bf16_f32 %0, %1, %2" : "=v"(r) : "v"(lo), "v"(hi));
  return r;
}

// ---------------- weight transposes ----------------
// wtb: bf16 A-frag order [k][mt(8)][kk(4)][lane(64)][j(8)] for de_w (147456)
// wob: bf16 A-frag order [k][mt(2)][kk(4)][lane(64)][j(8)] for off_w (36864)
// pwb: bf16 A-frag order [mt(8)][kk(4)][lane(64)][j(8)] for pw_w (16384)
__global__ void k_transpose_w(const float* __restrict__ de_w,
                              const float* __restrict__ off_w,
                              const float* __restrict__ pw_w,
                              short* __restrict__ wtb, short* __restrict__ wob,
                              short* __restrict__ pwb) {
  int i = blockIdx.x * 256 + threadIdx.x;
  if (i < 147456) {
    int j  = i & 7;
    int l  = (i >> 3) & 63;
    int kk = (i >> 9) & 3;
    int mt = (i >> 11) & 7;
    int k  = i >> 14;
    int oc = mt * 16 + (l & 15);
    int c  = kk * 32 + ((l >> 4) << 3) + j;
    wtb[i] = f2bf(de_w[(oc * 128 + c) * 9 + k]);
  }
  if (i < 36864) {
    int j  = i & 7;
    int l  = (i >> 3) & 63;
    int kk = (i >> 9) & 3;
    int mt = (i >> 11) & 1;
    int k  = i >> 12;
    int oc = mt * 16 + (l & 15);
    int c  = kk * 32 + ((l >> 4) << 3) + j;
    wob[i] = (oc < 18) ? f2bf(off_w[(oc * 128 + c) * 9 + k]) : (short)0;
  }
  if (i < 16384) {
    int j  = i & 7;
    int l  = (i >> 3) & 63;
    int kk = (i >> 9) & 3;
    int mt = i >> 11;
    int oc = mt * 16 + (l & 15);
    int c  = kk * 32 + ((l >> 4) << 3) + j;
    pwb[i] = f2bf(pw_w[oc * 128 + c]);
  }
}

// ---------------- depthwise 3x3 + bias : NCHW in -> NCHW out ----------------
__global__ void k_dw(const float* __restrict__ x, const float* __restrict__ dw_w,
                     const float* __restrict__ dw_b, float* __restrict__ h1) {
  int i = blockIdx.x * 256 + threadIdx.x;
  if (i >= BHWC) return;
  int xx = i % 96; int yy = (i / 96) % 96; int c = (i / HW_) % 128; int b = i / BATCH_STRIDE;
  const float* xp = x + (b * 128 + c) * HW_;
  const float* wp = dw_w + c * 9;
  float acc = dw_b[c];
  #pragma unroll
  for (int dy = 0; dy < 3; ++dy) {
    int sy = yy + dy - 1;
    if (sy < 0 || sy >= 96) continue;
    #pragma unroll
    for (int dx = 0; dx < 3; ++dx) {
      int sx = xx + dx - 1;
      if (sx < 0 || sx >= 96) continue;
      acc += xp[sy * 96 + sx] * wp[dy * 3 + dx];
    }
  }
  h1[i] = acc;
}

// ---------------- pointwise 1x1 + bias : MFMA bf16 -------------------------
// block = 64 pix x 128 oc, 4 waves; grid NPIX/64 = 576.
// Stage: thread (pixloc=tid&63, cq=tid>>6) reads h1 NCHW-coalesced (dword per
// channel-row), cvt_pk -> bf16 B-frags in LDS (lane-contiguous, conflict-free).
// MFMA: wave wv owns pixblk wv (16 pix) x all 8 mt; A from L1-hot pwb.
__global__ __launch_bounds__(256) void k_pw(
    const float* __restrict__ h1, const short* __restrict__ pwb,
    const float* __restrict__ pw_b, float* __restrict__ s) {
  __shared__ short lb[4][4][64][8];   // [pb][kk][lane][j], 16 KB
  int tid = threadIdx.x;
  int pixbase = blockIdx.x * 64;
  int b = pixbase / HW_;
  int hw0 = pixbase % HW_;

  int pixloc = tid & 63, cq = tid >> 6;
  {
    const float* hp = h1 + (size_t)b * BATCH_STRIDE + hw0 + pixloc;
    #pragma unroll
    for (int it = 0; it < 4; ++it) {
      int c8 = cq * 4 + it;
      int c0 = c8 * 8;
      float v[8];
      #pragma unroll
      for (int j = 0; j < 8; ++j)
        v[j] = hp[(size_t)(c0 + j) * HW_];
      unsigned o0 = cvtpk(v[0], v[1]), o1 = cvtpk(v[2], v[3]);
      unsigned o2 = cvtpk(v[4], v[5]), o3 = cvtpk(v[6], v[7]);
      *(uint4*)&lb[pixloc >> 4][c8 >> 2][(c8 & 3) * 16 + (pixloc & 15)][0] =
          make_uint4(o0, o1, o2, o3);
    }
  }
  __syncthreads();

  int lane = tid & 63, wv = tid >> 6;
  int lp = lane & 15, g = lane >> 4;
  const bfrag8* wp8 = (const bfrag8*)pwb;

  f32x4 acc[8];
  #pragma unroll
  for (int m = 0; m < 8; ++m) acc[m] = (f32x4){0.f, 0.f, 0.f, 0.f};

  #pragma unroll
  for (int kk = 0; kk < 4; ++kk) {
    bfrag8 Bf = *(const bfrag8*)&lb[wv][kk][lane][0];
    #pragma unroll
    for (int m = 0; m < 8; ++m) {
      bfrag8 af = wp8[((size_t)(m * 4 + kk)) * 64 + lane];
      acc[m] = __builtin_amdgcn_mfma_f32_16x16x32_bf16(af, Bf, acc[m], 0, 0, 0);
    }
  }

  int pix = pixbase + wv * 16 + lp;
  #pragma unroll
  for (int m = 0; m < 8; ++m) {
    int oc = m * 16 + g * 4;
    float4 bias = *(const float4*)(pw_b + oc);
    f32x4 a = acc[m];
    float4 v = make_float4(a[0] + bias.x, a[1] + bias.y, a[2] + bias.z, a[3] + bias.w);
    *(float4*)(s + (size_t)pix * 128 + oc) = v;
  }
}

// ---------------- InstanceNorm stats (per b,c over HW) ----------------
__global__ void k_instats(const float* __restrict__ s, float* __restrict__ ist) {
  int b = blockIdx.x / 36; int tile = blockIdx.x % 36;
  int c = threadIdx.x & 127; int half = threadIdx.x >> 7;
  const float* base = s + (size_t)(b * HW_ + tile * 256) * 128;
  float sum = 0.f, sq = 0.f;
  for (int p = half; p < 256; p += 2) {
    float v = base[p * 128 + c];
    sum += v; sq += v * v;
  }
  __shared__ float r1[256], r2[256];
  r1[threadIdx.x] = sum; r2[threadIdx.x] = sq;
  __syncthreads();
  if (half == 0) {
    atomicAdd(&ist[(b * 128 + c) * 2],     r1[c] + r1[c + 128]);
    atomicAdd(&ist[(b * 128 + c) * 2 + 1], r2[c] + r2[c + 128]);
  }
}

__global__ void k_infin(const float* __restrict__ ist, float* __restrict__ ifm,
                        float* __restrict__ ifr) {
  int i = blockIdx.x * 256 + threadIdx.x;
  if (i >= 512) return;
  float mean = ist[2 * i] * (1.f / 9216.f);
  float var  = ist[2 * i + 1] * (1.f / 9216.f) - mean * mean;
  ifm[i] = mean;
  ifr[i] = rsqrtf(var + 1e-5f);
}

// ---------------- normalize s -> bf16 pixel-major [pix][128] ---------------
__global__ __launch_bounds__(256) void k_norm(
    const float* __restrict__ s, const float* __restrict__ ifm,
    const float* __restrict__ ifr, short* __restrict__ nsamp) {
  int t = blockIdx.x * 256 + threadIdx.x;   // t < NPIX*16
  int pix = t >> 4; int c0 = (t & 15) * 8;
  int b = pix / HW_;
  const float* sp = s + (size_t)pix * 128 + c0;
  float4 a0 = *(const float4*)sp, a1 = *(const float4*)(sp + 4);
  float4 m0 = *(const float4*)(ifm + b * 128 + c0), m1 = *(const float4*)(ifm + b * 128 + c0 + 4);
  float4 r0 = *(const float4*)(ifr + b * 128 + c0), r1 = *(const float4*)(ifr + b * 128 + c0 + 4);
  bfrag8 o;
  o[0] = f2bf(fmaxf((a0.x - m0.x) * r0.x, 0.f));
  o[1] = f2bf(fmaxf((a0.y - m0.y) * r0.y, 0.f));
  o[2] = f2bf(fmaxf((a0.z - m0.z) * r0.z, 0.f));
  o[3] = f2bf(fmaxf((a0.w - m0.w) * r0.w, 0.f));
  o[4] = f2bf(fmaxf((a1.x - m1.x) * r1.x, 0.f));
  o[5] = f2bf(fmaxf((a1.y - m1.y) * r1.y, 0.f));
  o[6] = f2bf(fmaxf((a1.z - m1.z) * r1.z, 0.f));
  o[7] = f2bf(fmaxf((a1.w - m1.w) * r1.w, 0.f));
  *(bfrag8*)(nsamp + (size_t)pix * 128 + c0) = o;
}

// ---------------- offset conv as MFMA GEMM with shifted fragments ----------
// nsamp is pixel-major: frag element (q, kk, g) at bfrag8 index q*16 + kk*4 + g.
__global__ __launch_bounds__(256) void k_offgemm(
    const short* __restrict__ nsamp, const short* __restrict__ wob,
    const float* __restrict__ off_b, float* __restrict__ off) {
  int tid = threadIdx.x;
  int lane = tid & 63, wv = tid >> 6;
  int p0 = blockIdx.x * 128 + wv * 32;
  int lp = lane & 15, g = lane >> 4;
  const bfrag8* np = (const bfrag8*)nsamp;
  const bfrag8* wp = (const bfrag8*)wob;

  f32x4 acc[2][2];
  #pragma unroll
  for (int m = 0; m < 2; ++m)
    #pragma unroll
    for (int n = 0; n < 2; ++n) acc[m][n] = (f32x4){0.f, 0.f, 0.f, 0.f};

  int pn0 = p0 + lp, pn1 = p0 + 16 + lp;
  int x0_ = pn0 % 96, y0_ = (pn0 % HW_) / 96;
  int x1_ = pn1 % 96, y1_ = (pn1 % HW_) / 96;
  const bfrag8 zf = {0, 0, 0, 0, 0, 0, 0, 0};

  for (int k = 0; k < 9; ++k) {
    int dy = k / 3 - 1, dx = k % 3 - 1;
    int sh = dy * 96 + dx;
    bool v0 = ((unsigned)(x0_ + dx) < 96u) && ((unsigned)(y0_ + dy) < 96u);
    bool v1 = ((unsigned)(x1_ + dx) < 96u) && ((unsigned)(y1_ + dy) < 96u);
    int q0 = min(max(pn0 + sh, 0), NPIX - 1);
    int q1 = min(max(pn1 + sh, 0), NPIX - 1);
    size_t a0 = (size_t)q0 * 16 + g;
    size_t a1 = (size_t)q1 * 16 + g;
    #pragma unroll
    for (int kk = 0; kk < 4; ++kk) {
      bfrag8 B0 = np[a0 + kk * 4]; B0 = v0 ? B0 : zf;
      bfrag8 B1 = np[a1 + kk * 4]; B1 = v1 ? B1 : zf;
      bfrag8 A0 = wp[((size_t)(k * 2 + 0) * 4 + kk) * 64 + lane];
      bfrag8 A1 = wp[((size_t)(k * 2 + 1) * 4 + kk) * 64 + lane];
      acc[0][0] = __builtin_amdgcn_mfma_f32_16x16x32_bf16(A0, B0, acc[0][0], 0, 0, 0);
      acc[0][1] = __builtin_amdgcn_mfma_f32_16x16x32_bf16(A0, B1, acc[0][1], 0, 0, 0);
      acc[1][0] = __builtin_amdgcn_mfma_f32_16x16x32_bf16(A1, B0, acc[1][0], 0, 0, 0);
      acc[1][1] = __builtin_amdgcn_mfma_f32_16x16x32_bf16(A1, B1, acc[1][1], 0, 0, 0);
    }
  }

  #pragma unroll
  for (int mt = 0; mt < 2; ++mt) {
    #pragma unroll
    for (int r = 0; r < 4; ++r) {
      int oc = mt * 16 + g * 4 + r;
      if (oc < 18) {
        float bb = off_b[oc];
        off[(size_t)oc * NPIX + p0 + lp]      = acc[mt][0][r] + bb;
        off[(size_t)oc * NPIX + p0 + 16 + lp] = acc[mt][1][r] + bb;
      }
    }
  }
}

// ---------------- fused deform: sample->LDS (dbuf) + MFMA + GN stats --------
// block = 32 pix x 128 oc, 4 waves; grid 1152 (= 8*144, XCD-swizzled).
__global__ __launch_bounds__(256) void k_deform_f(
    const short* __restrict__ nsamp, const float* __restrict__ off,
    const short* __restrict__ wtb, const float* __restrict__ de_b,
    float* __restrict__ d, float* __restrict__ gst) {
  __shared__ short lbuf[2][2][16][17][8];  // 17.4 KB
  __shared__ float r1[256], r2[256];
  int tid = threadIdx.x;
  int bid = blockIdx.x;
  int wg = (bid & 7) * 144 + (bid >> 3);   // bijective for 1152
  int pixbase = wg * 32;

  int lane = tid & 63, wv = tid >> 6;
  int lp = lane & 15, g = lane >> 4;

  // sampling role: lane = (pq = lane>>4, ch = lane&15)
  int pq = lane >> 4, ch = lane & 15;

  // mfma role
  int mtg0 = wv * 2;
  const bfrag8* wp = (const bfrag8*)wtb;

  f32x4 acc[2][2];
  #pragma unroll
  for (int m = 0; m < 2; ++m)
    #pragma unroll
    for (int n = 0; n < 2; ++n) acc[m][n] = (f32x4){0.f, 0.f, 0.f, 0.f};

  auto SAMPLE = [&](int k, int buf) {
    #pragma unroll
    for (int q = 0; q < 2; ++q) {
      int lpix = wv * 8 + q * 4 + pq;        // local pixel 0..31
      int pix  = pixbase + lpix;
      int hw = pix % HW_;
      int ys = hw / 96, xs = hw % 96;
      int qb = (pix / HW_) * HW_;
      float dy = off[(size_t)(2 * k)     * NPIX + pix];
      float dx = off[(size_t)(2 * k + 1) * NPIX + pix];
      float py = (float)ys + (float)(k / 3 - 1) + dy;
      float px = (float)xs + (float)(k % 3 - 1) + dx;
      float y0f = floorf(py), x0f = floorf(px);
      float ly = py - y0f, lx = px - x0f;
      int y0 = (int)y0f, x0 = (int)x0f;
      bool vy0 = (y0 >= 0) && (y0 < 96), vy1 = (y0 + 1 >= 0) && (y0 + 1 < 96);
      bool vx0 = (x0 >= 0) && (x0 < 96), vx1 = (x0 + 1 >= 0) && (x0 + 1 < 96);
      float w00 = (vy0 && vx0) ? (1.f - ly) * (1.f - lx) : 0.f;
      float w01 = (vy0 && vx1) ? (1.f - ly) * lx : 0.f;
      float w10 = (vy1 && vx0) ? ly * (1.f - lx) : 0.f;
      float w11 = (vy1 && vx1) ? ly * lx : 0.f;
      int yc0 = min(max(y0, 0), 95), yc1 = min(max(y0 + 1, 0), 95);
      int xc0 = min(max(x0, 0), 95), xc1 = min(max(x0 + 1, 0), 95);
      const short* base = nsamp + (size_t)ch * 8;
      bfrag8 cA = *(const bfrag8*)(base + (size_t)(qb + yc0 * 96 + xc0) * 128);
      bfrag8 cB = *(const bfrag8*)(base + (size_t)(qb + yc0 * 96 + xc1) * 128);
      bfrag8 cC = *(const bfrag8*)(base + (size_t)(qb + yc1 * 96 + xc0) * 128);
      bfrag8 cD = *(const bfrag8*)(base + (size_t)(qb + yc1 * 96 + xc1) * 128);
      float v[8];
      #pragma unroll
      for (int j = 0; j < 8; ++j) {
        v[j] = bf2f(cA[j]) * w00 + bf2f(cB[j]) * w01
             + bf2f(cC[j]) * w10 + bf2f(cD[j]) * w11;
      }
      unsigned o[4];
      o[0] = cvtpk(v[0], v[1]);
      o[1] = cvtpk(v[2], v[3]);
      o[2] = cvtpk(v[4], v[5]);
      o[3] = cvtpk(v[6], v[7]);
      *(uint4*)&lbuf[buf][lpix >> 4][lpix & 15][ch][0] =
          make_uint4(o[0], o[1], o[2], o[3]);
    }
  };

  SAMPLE(0, 0);
  __syncthreads();
  for (int k = 0; k < 9; ++k) {
    int cur = k & 1;
    if (k < 8) SAMPLE(k + 1, cur ^ 1);
    #pragma unroll
    for (int kk = 0; kk < 4; ++kk) {
      bfrag8 B0 = *(const bfrag8*)&lbuf[cur][0][lp][kk * 4 + g][0];
      bfrag8 B1 = *(const bfrag8*)&lbuf[cur][1][lp][kk * 4 + g][0];
      #pragma unroll
      for (int m = 0; m < 2; ++m) {
        bfrag8 af = wp[((size_t)((k * 8 + mtg0 + m) * 4 + kk)) * 64 + lane];
        acc[m][0] = __builtin_amdgcn_mfma_f32_16x16x32_bf16(af, B0, acc[m][0], 0, 0, 0);
        acc[m][1] = __builtin_amdgcn_mfma_f32_16x16x32_bf16(af, B1, acc[m][1], 0, 0, 0);
      }
    }
    __syncthreads();
  }

  // epilogue: bias + store + GN partials. D: lane l reg r -> oc_local=(l>>4)*4+r, pix=l&15
  float lsum = 0.f, lsq = 0.f;
  #pragma unroll
  for (int m = 0; m < 2; ++m) {
    int oc = (mtg0 + m) * 16 + g * 4;
    float4 bias = *(const float4*)(de_b + oc);
    #pragma unroll
    for (int n = 0; n < 2; ++n) {
      int pix = pixbase + n * 16 + lp;
      f32x4 a = acc[m][n];
      float4 v = make_float4(a[0] + bias.x, a[1] + bias.y, a[2] + bias.z, a[3] + bias.w);
      *(float4*)(d + (size_t)pix * 128 + oc) = v;
      lsum += v.x + v.y + v.z + v.w;
      lsq  += v.x * v.x + v.y * v.y + v.z * v.z + v.w * v.w;
    }
  }
  r1[tid] = lsum; r2[tid] = lsq;
  __syncthreads();
  for (int st = 128; st > 0; st >>= 1) {
    if (tid < st) { r1[tid] += r1[tid + st]; r2[tid] += r2[tid + st]; }
    __syncthreads();
  }
  if (tid == 0) {
    int b = pixbase / HW_;
    atomicAdd(&gst[b * 2],     r1[0]);
    atomicAdd(&gst[b * 2 + 1], r2[0]);
  }
}

__global__ void k_gnfin(const float* __restrict__ gst, float* __restrict__ gfin) {
  int b = threadIdx.x;
  if (b >= 4) return;
  const float invN = 1.f / (float)BATCH_STRIDE;
  float mean = gst[2 * b] * invN;
  float var  = gst[2 * b + 1] * invN - mean * mean;
  gfin[2 * b] = mean;
  gfin[2 * b + 1] = rsqrtf(var + 1e-5f);
}

// ---------------- final: GN + sigmoid gate + shortcut, LDS transpose --------
__global__ __launch_bounds__(256) void k_final(
    const float* __restrict__ d, const float* __restrict__ s,
    const float* __restrict__ ifm, const float* __restrict__ ifr,
    const float* __restrict__ gfin, const float* __restrict__ gn_w,
    const float* __restrict__ gn_b, float* __restrict__ out) {
  __shared__ float t[128 * 33];
  int tid = threadIdx.x;
  int pixbase = blockIdx.x * 32;
  int b = pixbase / HW_;
  int hw0 = pixbase % HW_;
  float gm = gfin[2 * b], gr = gfin[2 * b + 1];

  int px0 = tid >> 3;
  int c0  = (tid & 7) * 16;
  const float* dp = d + ((size_t)(pixbase + px0)) * 128;
  const float* sp = s + ((size_t)(pixbase + px0)) * 128;
  #pragma unroll
  for (int q = 0; q < 4; ++q) {
    int c = c0 + q * 4;
    float4 dv = *(const float4*)(dp + c);
    float4 sv = *(const float4*)(sp + c);
    float4 m4 = *(const float4*)(ifm + b * 128 + c);
    float4 r4 = *(const float4*)(ifr + b * 128 + c);
    float4 w4 = *(const float4*)(gn_w + c);
    float4 b4 = *(const float4*)(gn_b + c);
    float svn, dn, gg;
    svn = fmaxf((sv.x - m4.x) * r4.x, 0.f);
    dn  = (dv.x - gm) * gr * w4.x + b4.x;
    gg  = 1.f / (1.f + expf(-dn));
    t[(c + 0) * 33 + px0] = svn * (1.f + gg);
    svn = fmaxf((sv.y - m4.y) * r4.y, 0.f);
    dn  = (dv.y - gm) * gr * w4.y + b4.y;
    gg  = 1.f / (1.f + expf(-dn));
    t[(c + 1) * 33 + px0] = svn * (1.f + gg);
    svn = fmaxf((sv.z - m4.z) * r4.z, 0.f);
    dn  = (dv.z - gm) * gr * w4.z + b4.z;
    gg  = 1.f / (1.f + expf(-dn));
    t[(c + 2) * 33 + px0] = svn * (1.f + gg);
    svn = fmaxf((sv.w - m4.w) * r4.w, 0.f);
    dn  = (dv.w - gm) * gr * w4.w + b4.w;
    gg  = 1.f / (1.f + expf(-dn));
    t[(c + 3) * 33 + px0] = svn * (1.f + gg);
  }
  __syncthreads();
  if (tid < 128) {
    float* op = out + (size_t)(b * 128 + tid) * HW_ + hw0;
    #pragma unroll
    for (int p4 = 0; p4 < 8; ++p4) {
      float4 v = make_float4(t[tid * 33 + p4 * 4], t[tid * 33 + p4 * 4 + 1],
                             t[tid * 33 + p4 * 4 + 2], t[tid * 33 + p4 * 4 + 3]);
      *(float4*)(op + p4 * 4) = v;
    }
  }
}

extern "C" void kernel_launch(void* const* d_in, const int* in_sizes, int n_in,
                              void* d_out, int out_size, void* d_ws, size_t ws_size,
                              hipStream_t stream) {
  (void)in_sizes; (void)n_in; (void)out_size; (void)ws_size;
  const float* x     = (const float*)d_in[0];
  const float* dw_w  = (const float*)d_in[1];
  const float* dw_b  = (const float*)d_in[2];
  const float* pw_w  = (const float*)d_in[3];
  const float* pw_b  = (const float*)d_in[4];
  const float* off_w = (const float*)d_in[5];
  const float* off_b = (const float*)d_in[6];
  const float* de_w  = (const float*)d_in[7];
  const float* de_b  = (const float*)d_in[8];
  const float* gn_w  = (const float*)d_in[9];
  const float* gn_b  = (const float*)d_in[10];
  float* out = (float*)d_out;

  float* ws   = (float*)d_ws;
  float* h1   = ws;                 // NCHW depthwise out; reused as deform out d (BHWC)
  float* s    = h1 + BHWC;          // BHWC raw pw output (normalized on the fly)
  float* off  = s + BHWC;           // [18][NPIX] offsets (oc-major)
  short* wtb  = (short*)(off + NPIX * 18);  // bf16 A-frag de_w (147456 shorts)
  short* wob  = wtb + 147456;       // bf16 A-frag off_w (36864 shorts)
  short* pwb  = wob + 36864;        // bf16 A-frag pw_w (16384 shorts; slot sized 16384 floats)
  float* ist  = (float*)(wob + 36864) + 16384;  // [B][C][2] sum,sumsq
  float* ifm  = ist + 1024;         // [B][C] mean
  float* ifr  = ifm + 512;          // [B][C] rstd
  float* gst  = ifr + 512;          // [B][2]
  float* gfin = gst + 8;            // [B][2]
  short* nsamp = (short*)(gfin + 8);        // bf16 normalized s, pixel-major (NPIX*128)

  hipMemsetAsync(ist, 0, (1024 + 512 + 512 + 8 + 8) * sizeof(float), stream);

  k_transpose_w<<<576, 256, 0, stream>>>(de_w, off_w, pw_w, wtb, wob, pwb);
  k_dw<<<BHWC / 256, 256, 0, stream>>>(x, dw_w, dw_b, h1);
  k_pw<<<NPIX / 64, 256, 0, stream>>>(h1, pwb, pw_b, s);
  k_instats<<<4 * 36, 256, 0, stream>>>(s, ist);
  k_infin<<<2, 256, 0, stream>>>(ist, ifm, ifr);
  k_norm<<<NPIX * 16 / 256, 256, 0, stream>>>(s, ifm, ifr, nsamp);
  k_offgemm<<<NPIX / 128, 256, 0, stream>>>(nsamp, wob, off_b, off);
  k_deform_f<<<NPIX / 32, 256, 0, stream>>>(nsamp, off, wtb, de_b, h1, gst);
  k_gnfin<<<1, 64, 0, stream>>>(gst, gfin);
  k_final<<<NPIX / 32, 256, 0, stream>>>(h1, s, ifm, ifr, gfin, gn_w, gn_b, out);
}

// Round 14
// 190.846 us; speedup vs baseline: 1.1828x; 1.0607x over previous
//
#include <hip/hip_runtime.h>
#include <hip/hip_bf16.h>
#include <math.h>

#define B_    4
#define C_    128
#define H_    96
#define W_    96
#define HW_   9216          // H*W
#define NPIX  36864         // B*HW
#define BHWC  4718592       // B*HW*C
#define BATCH_STRIDE 1179648 // HW*C

typedef __attribute__((ext_vector_type(8))) short bfrag8;
typedef __attribute__((ext_vector_type(4))) float f32x4;

static __device__ __forceinline__ short f2bf(float f) {
  __hip_bfloat16 h = __float2bfloat16(f);
  short s;
  __builtin_memcpy(&s, &h, 2);
  return s;
}
static __device__ __forceinline__ float bf2f(short s) {
  unsigned u = ((unsigned)(unsigned short)s) << 16;
  float f;
  __builtin_memcpy(&f, &u, 4);
  return f;
}
// pack two f32 -> two bf16 (RNE) in one instruction
static __device__ __forceinline__ unsigned cvtpk(float lo, float hi) {
  unsigned r;
  asm("v_cvt_pk_bf16_f32 %0, %1, %2" : "=v"(r) : "v"(lo), "v"(hi));
  return r;
}

// ---------------- weight transposes ----------------
// wtb: bf16 A-frag order [k][mt(8)][kk(4)][lane(64)][j(8)] for de_w (147456)
// wob: bf16 A-frag order [k][mt(2)][kk(4)][lane(64)][j(8)] for off_w (36864)
// pwb: bf16 A-frag order [mt(8)][kk(4)][lane(64)][j(8)] for pw_w (16384)
__global__ void k_transpose_w(const float* __restrict__ de_w,
                              const float* __restrict__ off_w,
                              const float* __restrict__ pw_w,
                              short* __restrict__ wtb, short* __restrict__ wob,
                              short* __restrict__ pwb) {
  int i = blockIdx.x * 256 + threadIdx.x;
  if (i < 147456) {
    int j  = i & 7;
    int l  = (i >> 3) & 63;
    int kk = (i >> 9) & 3;
    int mt = (i >> 11) & 7;
    int k  = i >> 14;
    int oc = mt * 16 + (l & 15);
    int c  = kk * 32 + ((l >> 4) << 3) + j;
    wtb[i] = f2bf(de_w[(oc * 128 + c) * 9 + k]);
  }
  if (i < 36864) {
    int j  = i & 7;
    int l  = (i >> 3) & 63;
    int kk = (i >> 9) & 3;
    int mt = (i >> 11) & 1;
    int k  = i >> 12;
    int oc = mt * 16 + (l & 15);
    int c  = kk * 32 + ((l >> 4) << 3) + j;
    wob[i] = (oc < 18) ? f2bf(off_w[(oc * 128 + c) * 9 + k]) : (short)0;
  }
  if (i < 16384) {
    int j  = i & 7;
    int l  = (i >> 3) & 63;
    int kk = (i >> 9) & 3;
    int mt = i >> 11;
    int oc = mt * 16 + (l & 15);
    int c  = kk * 32 + ((l >> 4) << 3) + j;
    pwb[i] = f2bf(pw_w[oc * 128 + c]);
  }
}

// ---------------- depthwise 3x3 + bias : NCHW in -> NCHW out ----------------
__global__ void k_dw(const float* __restrict__ x, const float* __restrict__ dw_w,
                     const float* __restrict__ dw_b, float* __restrict__ h1) {
  int i = blockIdx.x * 256 + threadIdx.x;
  if (i >= BHWC) return;
  int xx = i % 96; int yy = (i / 96) % 96; int c = (i / HW_) % 128; int b = i / BATCH_STRIDE;
  const float* xp = x + (b * 128 + c) * HW_;
  const float* wp = dw_w + c * 9;
  float acc = dw_b[c];
  #pragma unroll
  for (int dy = 0; dy < 3; ++dy) {
    int sy = yy + dy - 1;
    if (sy < 0 || sy >= 96) continue;
    #pragma unroll
    for (int dx = 0; dx < 3; ++dx) {
      int sx = xx + dx - 1;
      if (sx < 0 || sx >= 96) continue;
      acc += xp[sy * 96 + sx] * wp[dy * 3 + dx];
    }
  }
  h1[i] = acc;
}

// ---------------- pointwise 1x1 + bias : MFMA bf16 -------------------------
__global__ __launch_bounds__(256) void k_pw(
    const float* __restrict__ h1, const short* __restrict__ pwb,
    const float* __restrict__ pw_b, float* __restrict__ s) {
  __shared__ short lb[4][4][64][8];   // [pb][kk][lane][j], 16 KB
  int tid = threadIdx.x;
  int pixbase = blockIdx.x * 64;
  int b = pixbase / HW_;
  int hw0 = pixbase % HW_;

  int pixloc = tid & 63, cq = tid >> 6;
  {
    const float* hp = h1 + (size_t)b * BATCH_STRIDE + hw0 + pixloc;
    #pragma unroll
    for (int it = 0; it < 4; ++it) {
      int c8 = cq * 4 + it;
      int c0 = c8 * 8;
      float v[8];
      #pragma unroll
      for (int j = 0; j < 8; ++j)
        v[j] = hp[(size_t)(c0 + j) * HW_];
      unsigned o0 = cvtpk(v[0], v[1]), o1 = cvtpk(v[2], v[3]);
      unsigned o2 = cvtpk(v[4], v[5]), o3 = cvtpk(v[6], v[7]);
      *(uint4*)&lb[pixloc >> 4][c8 >> 2][(c8 & 3) * 16 + (pixloc & 15)][0] =
          make_uint4(o0, o1, o2, o3);
    }
  }
  __syncthreads();

  int lane = tid & 63, wv = tid >> 6;
  int lp = lane & 15, g = lane >> 4;
  const bfrag8* wp8 = (const bfrag8*)pwb;

  f32x4 acc[8];
  #pragma unroll
  for (int m = 0; m < 8; ++m) acc[m] = (f32x4){0.f, 0.f, 0.f, 0.f};

  #pragma unroll
  for (int kk = 0; kk < 4; ++kk) {
    bfrag8 Bf = *(const bfrag8*)&lb[wv][kk][lane][0];
    #pragma unroll
    for (int m = 0; m < 8; ++m) {
      bfrag8 af = wp8[((size_t)(m * 4 + kk)) * 64 + lane];
      acc[m] = __builtin_amdgcn_mfma_f32_16x16x32_bf16(af, Bf, acc[m], 0, 0, 0);
    }
  }

  int pix = pixbase + wv * 16 + lp;
  #pragma unroll
  for (int m = 0; m < 8; ++m) {
    int oc = m * 16 + g * 4;
    float4 bias = *(const float4*)(pw_b + oc);
    f32x4 a = acc[m];
    float4 v = make_float4(a[0] + bias.x, a[1] + bias.y, a[2] + bias.z, a[3] + bias.w);
    *(float4*)(s + (size_t)pix * 128 + oc) = v;
  }
}

// ---------------- InstanceNorm stats (per b,c over HW) ----------------
__global__ void k_instats(const float* __restrict__ s, float* __restrict__ ist) {
  int b = blockIdx.x / 36; int tile = blockIdx.x % 36;
  int c = threadIdx.x & 127; int half = threadIdx.x >> 7;
  const float* base = s + (size_t)(b * HW_ + tile * 256) * 128;
  float sum = 0.f, sq = 0.f;
  for (int p = half; p < 256; p += 2) {
    float v = base[p * 128 + c];
    sum += v; sq += v * v;
  }
  __shared__ float r1[256], r2[256];
  r1[threadIdx.x] = sum; r2[threadIdx.x] = sq;
  __syncthreads();
  if (half == 0) {
    atomicAdd(&ist[(b * 128 + c) * 2],     r1[c] + r1[c + 128]);
    atomicAdd(&ist[(b * 128 + c) * 2 + 1], r2[c] + r2[c + 128]);
  }
}

__global__ void k_infin(const float* __restrict__ ist, float* __restrict__ ifm,
                        float* __restrict__ ifr) {
  int i = blockIdx.x * 256 + threadIdx.x;
  if (i >= 512) return;
  float mean = ist[2 * i] * (1.f / 9216.f);
  float var  = ist[2 * i + 1] * (1.f / 9216.f) - mean * mean;
  ifm[i] = mean;
  ifr[i] = rsqrtf(var + 1e-5f);
}

// ---------------- normalize s -> bf16 pixel-major [pix][128] ---------------
__global__ __launch_bounds__(256) void k_norm(
    const float* __restrict__ s, const float* __restrict__ ifm,
    const float* __restrict__ ifr, short* __restrict__ nsamp) {
  int t = blockIdx.x * 256 + threadIdx.x;   // t < NPIX*16
  int pix = t >> 4; int c0 = (t & 15) * 8;
  int b = pix / HW_;
  const float* sp = s + (size_t)pix * 128 + c0;
  float4 a0 = *(const float4*)sp, a1 = *(const float4*)(sp + 4);
  float4 m0 = *(const float4*)(ifm + b * 128 + c0), m1 = *(const float4*)(ifm + b * 128 + c0 + 4);
  float4 r0 = *(const float4*)(ifr + b * 128 + c0), r1 = *(const float4*)(ifr + b * 128 + c0 + 4);
  bfrag8 o;
  o[0] = f2bf(fmaxf((a0.x - m0.x) * r0.x, 0.f));
  o[1] = f2bf(fmaxf((a0.y - m0.y) * r0.y, 0.f));
  o[2] = f2bf(fmaxf((a0.z - m0.z) * r0.z, 0.f));
  o[3] = f2bf(fmaxf((a0.w - m0.w) * r0.w, 0.f));
  o[4] = f2bf(fmaxf((a1.x - m1.x) * r1.x, 0.f));
  o[5] = f2bf(fmaxf((a1.y - m1.y) * r1.y, 0.f));
  o[6] = f2bf(fmaxf((a1.z - m1.z) * r1.z, 0.f));
  o[7] = f2bf(fmaxf((a1.w - m1.w) * r1.w, 0.f));
  *(bfrag8*)(nsamp + (size_t)pix * 128 + c0) = o;
}

// ---------------- offset conv as MFMA GEMM with shifted fragments ----------
__global__ __launch_bounds__(256) void k_offgemm(
    const short* __restrict__ nsamp, const short* __restrict__ wob,
    const float* __restrict__ off_b, float* __restrict__ off) {
  int tid = threadIdx.x;
  int lane = tid & 63, wv = tid >> 6;
  int p0 = blockIdx.x * 128 + wv * 32;
  int lp = lane & 15, g = lane >> 4;
  const bfrag8* np = (const bfrag8*)nsamp;
  const bfrag8* wp = (const bfrag8*)wob;

  f32x4 acc[2][2];
  #pragma unroll
  for (int m = 0; m < 2; ++m)
    #pragma unroll
    for (int n = 0; n < 2; ++n) acc[m][n] = (f32x4){0.f, 0.f, 0.f, 0.f};

  int pn0 = p0 + lp, pn1 = p0 + 16 + lp;
  int x0_ = pn0 % 96, y0_ = (pn0 % HW_) / 96;
  int x1_ = pn1 % 96, y1_ = (pn1 % HW_) / 96;
  const bfrag8 zf = {0, 0, 0, 0, 0, 0, 0, 0};

  for (int k = 0; k < 9; ++k) {
    int dy = k / 3 - 1, dx = k % 3 - 1;
    int sh = dy * 96 + dx;
    bool v0 = ((unsigned)(x0_ + dx) < 96u) && ((unsigned)(y0_ + dy) < 96u);
    bool v1 = ((unsigned)(x1_ + dx) < 96u) && ((unsigned)(y1_ + dy) < 96u);
    int q0 = min(max(pn0 + sh, 0), NPIX - 1);
    int q1 = min(max(pn1 + sh, 0), NPIX - 1);
    size_t a0 = (size_t)q0 * 16 + g;
    size_t a1 = (size_t)q1 * 16 + g;
    #pragma unroll
    for (int kk = 0; kk < 4; ++kk) {
      bfrag8 B0 = np[a0 + kk * 4]; B0 = v0 ? B0 : zf;
      bfrag8 B1 = np[a1 + kk * 4]; B1 = v1 ? B1 : zf;
      bfrag8 A0 = wp[((size_t)(k * 2 + 0) * 4 + kk) * 64 + lane];
      bfrag8 A1 = wp[((size_t)(k * 2 + 1) * 4 + kk) * 64 + lane];
      acc[0][0] = __builtin_amdgcn_mfma_f32_16x16x32_bf16(A0, B0, acc[0][0], 0, 0, 0);
      acc[0][1] = __builtin_amdgcn_mfma_f32_16x16x32_bf16(A0, B1, acc[0][1], 0, 0, 0);
      acc[1][0] = __builtin_amdgcn_mfma_f32_16x16x32_bf16(A1, B0, acc[1][0], 0, 0, 0);
      acc[1][1] = __builtin_amdgcn_mfma_f32_16x16x32_bf16(A1, B1, acc[1][1], 0, 0, 0);
    }
  }

  #pragma unroll
  for (int mt = 0; mt < 2; ++mt) {
    #pragma unroll
    for (int r = 0; r < 4; ++r) {
      int oc = mt * 16 + g * 4 + r;
      if (oc < 18) {
        float bb = off_b[oc];
        off[(size_t)oc * NPIX + p0 + lp]      = acc[mt][0][r] + bb;
        off[(size_t)oc * NPIX + p0 + 16 + lp] = acc[mt][1][r] + bb;
      }
    }
  }
}

// ---------------- fused deform: T14 async ISSUE/FINISH + MFMA + GN stats ----
// block = 32 pix x 128 oc, 4 waves; grid 1152 (= 8*144, XCD-swizzled).
// Offsets prefetched to LDS (kills 400cy off-load from per-tap chain).
// ISSUE(k+1) fires corner gathers into regs BEFORE FINISH(k) blends tap k:
// gathers fly across FINISH VALU + barrier + MFMA (reg loads survive barriers).
// Full unroll keeps corner-register indexing static (no scratch).
__global__ __launch_bounds__(256) void k_deform_f(
    const short* __restrict__ nsamp, const float* __restrict__ off,
    const short* __restrict__ wtb, const float* __restrict__ de_b,
    float* __restrict__ d, float* __restrict__ gst) {
  __shared__ short lbuf[2][2][16][17][8];  // 17.4 KB (R12 layout: reads/writes 2-way)
  __shared__ float offl[18][32];           // 2.3 KB
  __shared__ float r1[256], r2[256];
  int tid = threadIdx.x;
  int bid = blockIdx.x;
  int wg = (bid & 7) * 144 + (bid >> 3);   // bijective for 1152
  int pixbase = wg * 32;

  int lane = tid & 63, wv = tid >> 6;
  int lp = lane & 15, g = lane >> 4;
  int pq = lane >> 4, ch = lane & 15;      // sampling role

  // stage offsets for this block's 32 pixels: 18 x 32 floats
  #pragma unroll
  for (int t = 0; t < 3; ++t) {
    int i = t * 256 + tid;
    if (i < 576)
      offl[i >> 5][i & 31] = off[(size_t)(i >> 5) * NPIX + pixbase + (i & 31)];
  }
  __syncthreads();

  // per-q pixel constants (sampling role)
  int lpixA[2], ysA[2], xsA[2], qbA[2];
  #pragma unroll
  for (int q = 0; q < 2; ++q) {
    int lpix = wv * 8 + q * 4 + pq;
    int pix = pixbase + lpix;
    int hw = pix % HW_;
    lpixA[q] = lpix;
    ysA[q] = hw / 96;
    xsA[q] = hw % 96;
    qbA[q] = (pix / HW_) * HW_;
  }

  // mfma role
  int mtg0 = wv * 2;
  const bfrag8* wp = (const bfrag8*)wtb;

  f32x4 acc[2][2];
  #pragma unroll
  for (int m = 0; m < 2; ++m)
    #pragma unroll
    for (int n = 0; n < 2; ++n) acc[m][n] = (f32x4){0.f, 0.f, 0.f, 0.f};

  bfrag8 cs0[2][4], cs1[2][4];   // two corner-register sets

  auto ISSUE = [&](int k, bfrag8 (&cs)[2][4]) {
    #pragma unroll
    for (int q = 0; q < 2; ++q) {
      float dy = offl[2 * k][lpixA[q]];
      float dx = offl[2 * k + 1][lpixA[q]];
      float py = (float)ysA[q] + (float)(k / 3 - 1) + dy;
      float px = (float)xsA[q] + (float)(k % 3 - 1) + dx;
      int y0 = (int)floorf(py), x0 = (int)floorf(px);
      int yc0 = min(max(y0, 0), 95), yc1 = min(max(y0 + 1, 0), 95);
      int xc0 = min(max(x0, 0), 95), xc1 = min(max(x0 + 1, 0), 95);
      const short* base = nsamp + (size_t)ch * 8;
      cs[q][0] = *(const bfrag8*)(base + (size_t)(qbA[q] + yc0 * 96 + xc0) * 128);
      cs[q][1] = *(const bfrag8*)(base + (size_t)(qbA[q] + yc0 * 96 + xc1) * 128);
      cs[q][2] = *(const bfrag8*)(base + (size_t)(qbA[q] + yc1 * 96 + xc0) * 128);
      cs[q][3] = *(const bfrag8*)(base + (size_t)(qbA[q] + yc1 * 96 + xc1) * 128);
    }
  };

  auto FINISH = [&](int k, bfrag8 (&cs)[2][4], int buf) {
    #pragma unroll
    for (int q = 0; q < 2; ++q) {
      float dy = offl[2 * k][lpixA[q]];
      float dx = offl[2 * k + 1][lpixA[q]];
      float py = (float)ysA[q] + (float)(k / 3 - 1) + dy;
      float px = (float)xsA[q] + (float)(k % 3 - 1) + dx;
      float y0f = floorf(py), x0f = floorf(px);
      float ly = py - y0f, lx = px - x0f;
      int y0 = (int)y0f, x0 = (int)x0f;
      bool vy0 = (y0 >= 0) && (y0 < 96), vy1 = (y0 + 1 >= 0) && (y0 + 1 < 96);
      bool vx0 = (x0 >= 0) && (x0 < 96), vx1 = (x0 + 1 >= 0) && (x0 + 1 < 96);
      float w00 = (vy0 && vx0) ? (1.f - ly) * (1.f - lx) : 0.f;
      float w01 = (vy0 && vx1) ? (1.f - ly) * lx : 0.f;
      float w10 = (vy1 && vx0) ? ly * (1.f - lx) : 0.f;
      float w11 = (vy1 && vx1) ? ly * lx : 0.f;
      float v[8];
      #pragma unroll
      for (int j = 0; j < 8; ++j) {
        v[j] = bf2f(cs[q][0][j]) * w00 + bf2f(cs[q][1][j]) * w01
             + bf2f(cs[q][2][j]) * w10 + bf2f(cs[q][3][j]) * w11;
      }
      unsigned o0 = cvtpk(v[0], v[1]), o1 = cvtpk(v[2], v[3]);
      unsigned o2 = cvtpk(v[4], v[5]), o3 = cvtpk(v[6], v[7]);
      int lpix = lpixA[q];
      *(uint4*)&lbuf[buf][lpix >> 4][lpix & 15][ch][0] = make_uint4(o0, o1, o2, o3);
    }
  };

  ISSUE(0, cs0);
  #pragma unroll
  for (int k = 0; k < 9; ++k) {
    if (k < 8) {
      if ((k + 1) & 1) ISSUE(k + 1, cs1);
      else             ISSUE(k + 1, cs0);
    }
    if (k & 1) FINISH(k, cs1, 1);
    else       FINISH(k, cs0, 0);
    __syncthreads();
    int cur = k & 1;
    #pragma unroll
    for (int kk = 0; kk < 4; ++kk) {
      bfrag8 B0 = *(const bfrag8*)&lbuf[cur][0][lp][kk * 4 + g][0];
      bfrag8 B1 = *(const bfrag8*)&lbuf[cur][1][lp][kk * 4 + g][0];
      #pragma unroll
      for (int m = 0; m < 2; ++m) {
        bfrag8 af = wp[((size_t)((k * 8 + mtg0 + m) * 4 + kk)) * 64 + lane];
        acc[m][0] = __builtin_amdgcn_mfma_f32_16x16x32_bf16(af, B0, acc[m][0], 0, 0, 0);
        acc[m][1] = __builtin_amdgcn_mfma_f32_16x16x32_bf16(af, B1, acc[m][1], 0, 0, 0);
      }
    }
  }

  // epilogue: bias + store + GN partials. D: lane l reg r -> oc_local=(l>>4)*4+r, pix=l&15
  float lsum = 0.f, lsq = 0.f;
  #pragma unroll
  for (int m = 0; m < 2; ++m) {
    int oc = (mtg0 + m) * 16 + g * 4;
    float4 bias = *(const float4*)(de_b + oc);
    #pragma unroll
    for (int n = 0; n < 2; ++n) {
      int pix = pixbase + n * 16 + lp;
      f32x4 a = acc[m][n];
      float4 v = make_float4(a[0] + bias.x, a[1] + bias.y, a[2] + bias.z, a[3] + bias.w);
      *(float4*)(d + (size_t)pix * 128 + oc) = v;
      lsum += v.x + v.y + v.z + v.w;
      lsq  += v.x * v.x + v.y * v.y + v.z * v.z + v.w * v.w;
    }
  }
  __syncthreads();
  r1[tid] = lsum; r2[tid] = lsq;
  __syncthreads();
  for (int st = 128; st > 0; st >>= 1) {
    if (tid < st) { r1[tid] += r1[tid + st]; r2[tid] += r2[tid + st]; }
    __syncthreads();
  }
  if (tid == 0) {
    int b = pixbase / HW_;
    atomicAdd(&gst[b * 2],     r1[0]);
    atomicAdd(&gst[b * 2 + 1], r2[0]);
  }
}

__global__ void k_gnfin(const float* __restrict__ gst, float* __restrict__ gfin) {
  int b = threadIdx.x;
  if (b >= 4) return;
  const float invN = 1.f / (float)BATCH_STRIDE;
  float mean = gst[2 * b] * invN;
  float var  = gst[2 * b + 1] * invN - mean * mean;
  gfin[2 * b] = mean;
  gfin[2 * b + 1] = rsqrtf(var + 1e-5f);
}

// ---------------- final: GN + sigmoid gate + shortcut, LDS transpose --------
__global__ __launch_bounds__(256) void k_final(
    const float* __restrict__ d, const float* __restrict__ s,
    const float* __restrict__ ifm, const float* __restrict__ ifr,
    const float* __restrict__ gfin, const float* __restrict__ gn_w,
    const float* __restrict__ gn_b, float* __restrict__ out) {
  __shared__ float t[128 * 33];
  int tid = threadIdx.x;
  int pixbase = blockIdx.x * 32;
  int b = pixbase / HW_;
  int hw0 = pixbase % HW_;
  float gm = gfin[2 * b], gr = gfin[2 * b + 1];

  int px0 = tid >> 3;
  int c0  = (tid & 7) * 16;
  const float* dp = d + ((size_t)(pixbase + px0)) * 128;
  const float* sp = s + ((size_t)(pixbase + px0)) * 128;
  #pragma unroll
  for (int q = 0; q < 4; ++q) {
    int c = c0 + q * 4;
    float4 dv = *(const float4*)(dp + c);
    float4 sv = *(const float4*)(sp + c);
    float4 m4 = *(const float4*)(ifm + b * 128 + c);
    float4 r4 = *(const float4*)(ifr + b * 128 + c);
    float4 w4 = *(const float4*)(gn_w + c);
    float4 b4 = *(const float4*)(gn_b + c);
    float svn, dn, gg;
    svn = fmaxf((sv.x - m4.x) * r4.x, 0.f);
    dn  = (dv.x - gm) * gr * w4.x + b4.x;
    gg  = 1.f / (1.f + expf(-dn));
    t[(c + 0) * 33 + px0] = svn * (1.f + gg);
    svn = fmaxf((sv.y - m4.y) * r4.y, 0.f);
    dn  = (dv.y - gm) * gr * w4.y + b4.y;
    gg  = 1.f / (1.f + expf(-dn));
    t[(c + 1) * 33 + px0] = svn * (1.f + gg);
    svn = fmaxf((sv.z - m4.z) * r4.z, 0.f);
    dn  = (dv.z - gm) * gr * w4.z + b4.z;
    gg  = 1.f / (1.f + expf(-dn));
    t[(c + 2) * 33 + px0] = svn * (1.f + gg);
    svn = fmaxf((sv.w - m4.w) * r4.w, 0.f);
    dn  = (dv.w - gm) * gr * w4.w + b4.w;
    gg  = 1.f / (1.f + expf(-dn));
    t[(c + 3) * 33 + px0] = svn * (1.f + gg);
  }
  __syncthreads();
  if (tid < 128) {
    float* op = out + (size_t)(b * 128 + tid) * HW_ + hw0;
    #pragma unroll
    for (int p4 = 0; p4 < 8; ++p4) {
      float4 v = make_float4(t[tid * 33 + p4 * 4], t[tid * 33 + p4 * 4 + 1],
                             t[tid * 33 + p4 * 4 + 2], t[tid * 33 + p4 * 4 + 3]);
      *(float4*)(op + p4 * 4) = v;
    }
  }
}

extern "C" void kernel_launch(void* const* d_in, const int* in_sizes, int n_in,
                              void* d_out, int out_size, void* d_ws, size_t ws_size,
                              hipStream_t stream) {
  (void)in_sizes; (void)n_in; (void)out_size; (void)ws_size;
  const float* x     = (const float*)d_in[0];
  const float* dw_w  = (const float*)d_in[1];
  const float* dw_b  = (const float*)d_in[2];
  const float* pw_w  = (const float*)d_in[3];
  const float* pw_b  = (const float*)d_in[4];
  const float* off_w = (const float*)d_in[5];
  const float* off_b = (const float*)d_in[6];
  const float* de_w  = (const float*)d_in[7];
  const float* de_b  = (const float*)d_in[8];
  const float* gn_w  = (const float*)d_in[9];
  const float* gn_b  = (const float*)d_in[10];
  float* out = (float*)d_out;

  float* ws   = (float*)d_ws;
  float* h1   = ws;                 // NCHW depthwise out; reused as deform out d (BHWC)
  float* s    = h1 + BHWC;          // BHWC raw pw output (normalized on the fly)
  float* off  = s + BHWC;           // [18][NPIX] offsets (oc-major)
  short* wtb  = (short*)(off + NPIX * 18);  // bf16 A-frag de_w (147456 shorts)
  short* wob  = wtb + 147456;       // bf16 A-frag off_w (36864 shorts)
  short* pwb  = wob + 36864;        // bf16 A-frag pw_w (16384 shorts; slot sized 16384 floats)
  float* ist  = (float*)(wob + 36864) + 16384;  // [B][C][2] sum,sumsq
  float* ifm  = ist + 1024;         // [B][C] mean
  float* ifr  = ifm + 512;          // [B][C] rstd
  float* gst  = ifr + 512;          // [B][2]
  float* gfin = gst + 8;            // [B][2]
  short* nsamp = (short*)(gfin + 8);        // bf16 normalized s, pixel-major (NPIX*128)

  hipMemsetAsync(ist, 0, (1024 + 512 + 512 + 8 + 8) * sizeof(float), stream);

  k_transpose_w<<<576, 256, 0, stream>>>(de_w, off_w, pw_w, wtb, wob, pwb);
  k_dw<<<BHWC / 256, 256, 0, stream>>>(x, dw_w, dw_b, h1);
  k_pw<<<NPIX / 64, 256, 0, stream>>>(h1, pwb, pw_b, s);
  k_instats<<<4 * 36, 256, 0, stream>>>(s, ist);
  k_infin<<<2, 256, 0, stream>>>(ist, ifm, ifr);
  k_norm<<<NPIX * 16 / 256, 256, 0, stream>>>(s, ifm, ifr, nsamp);
  k_offgemm<<<NPIX / 128, 256, 0, stream>>>(nsamp, wob, off_b, off);
  k_deform_f<<<NPIX / 32, 256, 0, stream>>>(nsamp, off, wtb, de_b, h1, gst);
  k_gnfin<<<1, 64, 0, stream>>>(gst, gfin);
  k_final<<<NPIX / 32, 256, 0, stream>>>(h1, s, ifm, ifr, gfin, gn_w, gn_b, out);
}

// Round 15
// 165.328 us; speedup vs baseline: 1.3654x; 1.1544x over previous
//
#include <hip/hip_runtime.h>
#include <hip/hip_bf16.h>
#include <math.h>

#define B_    4
#define C_    128
#define H_    96
#define W_    96
#define HW_   9216          // H*W
#define NPIX  36864         // B*HW
#define BHWC  4718592       // B*HW*C
#define BATCH_STRIDE 1179648 // HW*C

typedef __attribute__((ext_vector_type(8))) short bfrag8;
typedef __attribute__((ext_vector_type(4))) float f32x4;

static __device__ __forceinline__ short f2bf(float f) {
  __hip_bfloat16 h = __float2bfloat16(f);
  short s;
  __builtin_memcpy(&s, &h, 2);
  return s;
}
static __device__ __forceinline__ float bf2f(short s) {
  unsigned u = ((unsigned)(unsigned short)s) << 16;
  float f;
  __builtin_memcpy(&f, &u, 4);
  return f;
}
// pack two f32 -> two bf16 (RNE) in one instruction
static __device__ __forceinline__ unsigned cvtpk(float lo, float hi) {
  unsigned r;
  asm("v_cvt_pk_bf16_f32 %0, %1, %2" : "=v"(r) : "v"(lo), "v"(hi));
  return r;
}

// ---------------- weight transposes ----------------
// wtb: bf16 A-frag order [k][mt(8)][kk(4)][lane(64)][j(8)] for de_w (147456)
// wob: bf16 A-frag order [k][mt(2)][kk(4)][lane(64)][j(8)] for off_w (36864)
// pwb: bf16 A-frag order [mt(8)][kk(4)][lane(64)][j(8)] for pw_w (16384)
__global__ void k_transpose_w(const float* __restrict__ de_w,
                              const float* __restrict__ off_w,
                              const float* __restrict__ pw_w,
                              short* __restrict__ wtb, short* __restrict__ wob,
                              short* __restrict__ pwb) {
  int i = blockIdx.x * 256 + threadIdx.x;
  if (i < 147456) {
    int j  = i & 7;
    int l  = (i >> 3) & 63;
    int kk = (i >> 9) & 3;
    int mt = (i >> 11) & 7;
    int k  = i >> 14;
    int oc = mt * 16 + (l & 15);
    int c  = kk * 32 + ((l >> 4) << 3) + j;
    wtb[i] = f2bf(de_w[(oc * 128 + c) * 9 + k]);
  }
  if (i < 36864) {
    int j  = i & 7;
    int l  = (i >> 3) & 63;
    int kk = (i >> 9) & 3;
    int mt = (i >> 11) & 1;
    int k  = i >> 12;
    int oc = mt * 16 + (l & 15);
    int c  = kk * 32 + ((l >> 4) << 3) + j;
    wob[i] = (oc < 18) ? f2bf(off_w[(oc * 128 + c) * 9 + k]) : (short)0;
  }
  if (i < 16384) {
    int j  = i & 7;
    int l  = (i >> 3) & 63;
    int kk = (i >> 9) & 3;
    int mt = i >> 11;
    int oc = mt * 16 + (l & 15);
    int c  = kk * 32 + ((l >> 4) << 3) + j;
    pwb[i] = f2bf(pw_w[oc * 128 + c]);
  }
}

// ---------------- depthwise 3x3 + bias : NCHW in -> NCHW out ----------------
__global__ void k_dw(const float* __restrict__ x, const float* __restrict__ dw_w,
                     const float* __restrict__ dw_b, float* __restrict__ h1) {
  int i = blockIdx.x * 256 + threadIdx.x;
  if (i >= BHWC) return;
  int xx = i % 96; int yy = (i / 96) % 96; int c = (i / HW_) % 128; int b = i / BATCH_STRIDE;
  const float* xp = x + (b * 128 + c) * HW_;
  const float* wp = dw_w + c * 9;
  float acc = dw_b[c];
  #pragma unroll
  for (int dy = 0; dy < 3; ++dy) {
    int sy = yy + dy - 1;
    if (sy < 0 || sy >= 96) continue;
    #pragma unroll
    for (int dx = 0; dx < 3; ++dx) {
      int sx = xx + dx - 1;
      if (sx < 0 || sx >= 96) continue;
      acc += xp[sy * 96 + sx] * wp[dy * 3 + dx];
    }
  }
  h1[i] = acc;
}

// ---------------- pointwise 1x1 + bias : MFMA bf16, fused IN-stats ---------
// block = 64 pix x 128 oc, 4 waves; grid NPIX/64 = 576.
// Epilogue: per-channel partials via shfl_xor over the 16 pixel-lanes +
// LDS wave-combine + 1 atomicAdd per channel (replaces k_instats).
__global__ __launch_bounds__(256) void k_pw(
    const float* __restrict__ h1, const short* __restrict__ pwb,
    const float* __restrict__ pw_b, float* __restrict__ s,
    float* __restrict__ ist) {
  __shared__ short lb[4][4][64][8];   // [pb][kk][lane][j], 16 KB
  __shared__ float ps[4][128], pq2[4][128];  // 4 KB stats partials
  int tid = threadIdx.x;
  int pixbase = blockIdx.x * 64;
  int b = pixbase / HW_;
  int hw0 = pixbase % HW_;

  int pixloc = tid & 63, cq = tid >> 6;
  {
    const float* hp = h1 + (size_t)b * BATCH_STRIDE + hw0 + pixloc;
    #pragma unroll
    for (int it = 0; it < 4; ++it) {
      int c8 = cq * 4 + it;
      int c0 = c8 * 8;
      float v[8];
      #pragma unroll
      for (int j = 0; j < 8; ++j)
        v[j] = hp[(size_t)(c0 + j) * HW_];
      unsigned o0 = cvtpk(v[0], v[1]), o1 = cvtpk(v[2], v[3]);
      unsigned o2 = cvtpk(v[4], v[5]), o3 = cvtpk(v[6], v[7]);
      *(uint4*)&lb[pixloc >> 4][c8 >> 2][(c8 & 3) * 16 + (pixloc & 15)][0] =
          make_uint4(o0, o1, o2, o3);
    }
  }
  __syncthreads();

  int lane = tid & 63, wv = tid >> 6;
  int lp = lane & 15, g = lane >> 4;
  const bfrag8* wp8 = (const bfrag8*)pwb;

  f32x4 acc[8];
  #pragma unroll
  for (int m = 0; m < 8; ++m) acc[m] = (f32x4){0.f, 0.f, 0.f, 0.f};

  #pragma unroll
  for (int kk = 0; kk < 4; ++kk) {
    bfrag8 Bf = *(const bfrag8*)&lb[wv][kk][lane][0];
    #pragma unroll
    for (int m = 0; m < 8; ++m) {
      bfrag8 af = wp8[((size_t)(m * 4 + kk)) * 64 + lane];
      acc[m] = __builtin_amdgcn_mfma_f32_16x16x32_bf16(af, Bf, acc[m], 0, 0, 0);
    }
  }

  int pix = pixbase + wv * 16 + lp;
  #pragma unroll
  for (int m = 0; m < 8; ++m) {
    int oc = m * 16 + g * 4;
    float4 bias = *(const float4*)(pw_b + oc);
    f32x4 a = acc[m];
    float4 v = make_float4(a[0] + bias.x, a[1] + bias.y, a[2] + bias.z, a[3] + bias.w);
    *(float4*)(s + (size_t)pix * 128 + oc) = v;
    // per-channel partial sums over the wave's 16 pixels (lp lanes)
    float t0 = v.x, t1 = v.y, t2 = v.z, t3 = v.w;
    float u0 = v.x * v.x, u1 = v.y * v.y, u2 = v.z * v.z, u3 = v.w * v.w;
    #pragma unroll
    for (int mask = 1; mask <= 8; mask <<= 1) {
      t0 += __shfl_xor(t0, mask); t1 += __shfl_xor(t1, mask);
      t2 += __shfl_xor(t2, mask); t3 += __shfl_xor(t3, mask);
      u0 += __shfl_xor(u0, mask); u1 += __shfl_xor(u1, mask);
      u2 += __shfl_xor(u2, mask); u3 += __shfl_xor(u3, mask);
    }
    if (lp == 0) {
      ps[wv][oc + 0] = t0; ps[wv][oc + 1] = t1; ps[wv][oc + 2] = t2; ps[wv][oc + 3] = t3;
      pq2[wv][oc + 0] = u0; pq2[wv][oc + 1] = u1; pq2[wv][oc + 2] = u2; pq2[wv][oc + 3] = u3;
    }
  }
  __syncthreads();
  if (tid < 128) {
    float su = ps[0][tid] + ps[1][tid] + ps[2][tid] + ps[3][tid];
    float sq = pq2[0][tid] + pq2[1][tid] + pq2[2][tid] + pq2[3][tid];
    atomicAdd(&ist[(size_t)(b * 128 + tid) * 2],     su);
    atomicAdd(&ist[(size_t)(b * 128 + tid) * 2 + 1], sq);
  }
}

// ---------------- normalize s -> bf16 pixel-major [pix][128] ---------------
// infin fused: mean/rstd derived from ist per thread (L1-hot broadcasts).
__global__ __launch_bounds__(256) void k_norm(
    const float* __restrict__ s, const float* __restrict__ ist,
    short* __restrict__ nsamp) {
  int t = blockIdx.x * 256 + threadIdx.x;   // t < NPIX*16
  int pix = t >> 4; int c0 = (t & 15) * 8;
  int b = pix / HW_;
  const float* sp = s + (size_t)pix * 128 + c0;
  float4 a0 = *(const float4*)sp, a1 = *(const float4*)(sp + 4);
  float v[8] = {a0.x, a0.y, a0.z, a0.w, a1.x, a1.y, a1.z, a1.w};
  bfrag8 o;
  #pragma unroll
  for (int j = 0; j < 8; ++j) {
    size_t ci = (size_t)(b * 128 + c0 + j) * 2;
    float mean = ist[ci] * (1.f / 9216.f);
    float var  = ist[ci + 1] * (1.f / 9216.f) - mean * mean;
    float rs = rsqrtf(var + 1e-5f);
    o[j] = f2bf(fmaxf((v[j] - mean) * rs, 0.f));
  }
  *(bfrag8*)(nsamp + (size_t)pix * 128 + c0) = o;
}

// ---------------- offset conv as MFMA GEMM with shifted fragments ----------
__global__ __launch_bounds__(256) void k_offgemm(
    const short* __restrict__ nsamp, const short* __restrict__ wob,
    const float* __restrict__ off_b, float* __restrict__ off) {
  int tid = threadIdx.x;
  int lane = tid & 63, wv = tid >> 6;
  int p0 = blockIdx.x * 128 + wv * 32;
  int lp = lane & 15, g = lane >> 4;
  const bfrag8* np = (const bfrag8*)nsamp;
  const bfrag8* wp = (const bfrag8*)wob;

  f32x4 acc[2][2];
  #pragma unroll
  for (int m = 0; m < 2; ++m)
    #pragma unroll
    for (int n = 0; n < 2; ++n) acc[m][n] = (f32x4){0.f, 0.f, 0.f, 0.f};

  int pn0 = p0 + lp, pn1 = p0 + 16 + lp;
  int x0_ = pn0 % 96, y0_ = (pn0 % HW_) / 96;
  int x1_ = pn1 % 96, y1_ = (pn1 % HW_) / 96;
  const bfrag8 zf = {0, 0, 0, 0, 0, 0, 0, 0};

  for (int k = 0; k < 9; ++k) {
    int dy = k / 3 - 1, dx = k % 3 - 1;
    int sh = dy * 96 + dx;
    bool v0 = ((unsigned)(x0_ + dx) < 96u) && ((unsigned)(y0_ + dy) < 96u);
    bool v1 = ((unsigned)(x1_ + dx) < 96u) && ((unsigned)(y1_ + dy) < 96u);
    int q0 = min(max(pn0 + sh, 0), NPIX - 1);
    int q1 = min(max(pn1 + sh, 0), NPIX - 1);
    size_t a0 = (size_t)q0 * 16 + g;
    size_t a1 = (size_t)q1 * 16 + g;
    #pragma unroll
    for (int kk = 0; kk < 4; ++kk) {
      bfrag8 B0 = np[a0 + kk * 4]; B0 = v0 ? B0 : zf;
      bfrag8 B1 = np[a1 + kk * 4]; B1 = v1 ? B1 : zf;
      bfrag8 A0 = wp[((size_t)(k * 2 + 0) * 4 + kk) * 64 + lane];
      bfrag8 A1 = wp[((size_t)(k * 2 + 1) * 4 + kk) * 64 + lane];
      acc[0][0] = __builtin_amdgcn_mfma_f32_16x16x32_bf16(A0, B0, acc[0][0], 0, 0, 0);
      acc[0][1] = __builtin_amdgcn_mfma_f32_16x16x32_bf16(A0, B1, acc[0][1], 0, 0, 0);
      acc[1][0] = __builtin_amdgcn_mfma_f32_16x16x32_bf16(A1, B0, acc[1][0], 0, 0, 0);
      acc[1][1] = __builtin_amdgcn_mfma_f32_16x16x32_bf16(A1, B1, acc[1][1], 0, 0, 0);
    }
  }

  #pragma unroll
  for (int mt = 0; mt < 2; ++mt) {
    #pragma unroll
    for (int r = 0; r < 4; ++r) {
      int oc = mt * 16 + g * 4 + r;
      if (oc < 18) {
        float bb = off_b[oc];
        off[(size_t)oc * NPIX + p0 + lp]      = acc[mt][0][r] + bb;
        off[(size_t)oc * NPIX + p0 + 16 + lp] = acc[mt][1][r] + bb;
      }
    }
  }
}

// ---------------- fused deform: T14 async ISSUE/FINISH + MFMA + GN stats ----
// block = 32 pix x 128 oc, 4 waves; grid 1152 (= 8*144, XCD-swizzled).
__global__ __launch_bounds__(256) void k_deform_f(
    const short* __restrict__ nsamp, const float* __restrict__ off,
    const short* __restrict__ wtb, const float* __restrict__ de_b,
    float* __restrict__ d, float* __restrict__ gst) {
  __shared__ short lbuf[2][2][16][17][8];  // 17.4 KB
  __shared__ float offl[18][32];           // 2.3 KB
  __shared__ float r1[256], r2[256];
  int tid = threadIdx.x;
  int bid = blockIdx.x;
  int wg = (bid & 7) * 144 + (bid >> 3);   // bijective for 1152
  int pixbase = wg * 32;

  int lane = tid & 63, wv = tid >> 6;
  int lp = lane & 15, g = lane >> 4;
  int pq = lane >> 4, ch = lane & 15;      // sampling role

  // stage offsets for this block's 32 pixels: 18 x 32 floats
  #pragma unroll
  for (int t = 0; t < 3; ++t) {
    int i = t * 256 + tid;
    if (i < 576)
      offl[i >> 5][i & 31] = off[(size_t)(i >> 5) * NPIX + pixbase + (i & 31)];
  }
  __syncthreads();

  // per-q pixel constants (sampling role)
  int lpixA[2], ysA[2], xsA[2], qbA[2];
  #pragma unroll
  for (int q = 0; q < 2; ++q) {
    int lpix = wv * 8 + q * 4 + pq;
    int pix = pixbase + lpix;
    int hw = pix % HW_;
    lpixA[q] = lpix;
    ysA[q] = hw / 96;
    xsA[q] = hw % 96;
    qbA[q] = (pix / HW_) * HW_;
  }

  // mfma role
  int mtg0 = wv * 2;
  const bfrag8* wp = (const bfrag8*)wtb;

  f32x4 acc[2][2];
  #pragma unroll
  for (int m = 0; m < 2; ++m)
    #pragma unroll
    for (int n = 0; n < 2; ++n) acc[m][n] = (f32x4){0.f, 0.f, 0.f, 0.f};

  bfrag8 cs0[2][4], cs1[2][4];   // two corner-register sets

  auto ISSUE = [&](int k, bfrag8 (&cs)[2][4]) {
    #pragma unroll
    for (int q = 0; q < 2; ++q) {
      float dy = offl[2 * k][lpixA[q]];
      float dx = offl[2 * k + 1][lpixA[q]];
      float py = (float)ysA[q] + (float)(k / 3 - 1) + dy;
      float px = (float)xsA[q] + (float)(k % 3 - 1) + dx;
      int y0 = (int)floorf(py), x0 = (int)floorf(px);
      int yc0 = min(max(y0, 0), 95), yc1 = min(max(y0 + 1, 0), 95);
      int xc0 = min(max(x0, 0), 95), xc1 = min(max(x0 + 1, 0), 95);
      const short* base = nsamp + (size_t)ch * 8;
      cs[q][0] = *(const bfrag8*)(base + (size_t)(qbA[q] + yc0 * 96 + xc0) * 128);
      cs[q][1] = *(const bfrag8*)(base + (size_t)(qbA[q] + yc0 * 96 + xc1) * 128);
      cs[q][2] = *(const bfrag8*)(base + (size_t)(qbA[q] + yc1 * 96 + xc0) * 128);
      cs[q][3] = *(const bfrag8*)(base + (size_t)(qbA[q] + yc1 * 96 + xc1) * 128);
    }
  };

  auto FINISH = [&](int k, bfrag8 (&cs)[2][4], int buf) {
    #pragma unroll
    for (int q = 0; q < 2; ++q) {
      float dy = offl[2 * k][lpixA[q]];
      float dx = offl[2 * k + 1][lpixA[q]];
      float py = (float)ysA[q] + (float)(k / 3 - 1) + dy;
      float px = (float)xsA[q] + (float)(k % 3 - 1) + dx;
      float y0f = floorf(py), x0f = floorf(px);
      float ly = py - y0f, lx = px - x0f;
      int y0 = (int)y0f, x0 = (int)x0f;
      bool vy0 = (y0 >= 0) && (y0 < 96), vy1 = (y0 + 1 >= 0) && (y0 + 1 < 96);
      bool vx0 = (x0 >= 0) && (x0 < 96), vx1 = (x0 + 1 >= 0) && (x0 + 1 < 96);
      float w00 = (vy0 && vx0) ? (1.f - ly) * (1.f - lx) : 0.f;
      float w01 = (vy0 && vx1) ? (1.f - ly) * lx : 0.f;
      float w10 = (vy1 && vx0) ? ly * (1.f - lx) : 0.f;
      float w11 = (vy1 && vx1) ? ly * lx : 0.f;
      float v[8];
      #pragma unroll
      for (int j = 0; j < 8; ++j) {
        v[j] = bf2f(cs[q][0][j]) * w00 + bf2f(cs[q][1][j]) * w01
             + bf2f(cs[q][2][j]) * w10 + bf2f(cs[q][3][j]) * w11;
      }
      unsigned o0 = cvtpk(v[0], v[1]), o1 = cvtpk(v[2], v[3]);
      unsigned o2 = cvtpk(v[4], v[5]), o3 = cvtpk(v[6], v[7]);
      int lpix = lpixA[q];
      *(uint4*)&lbuf[buf][lpix >> 4][lpix & 15][ch][0] = make_uint4(o0, o1, o2, o3);
    }
  };

  ISSUE(0, cs0);
  #pragma unroll
  for (int k = 0; k < 9; ++k) {
    if (k < 8) {
      if ((k + 1) & 1) ISSUE(k + 1, cs1);
      else             ISSUE(k + 1, cs0);
    }
    if (k & 1) FINISH(k, cs1, 1);
    else       FINISH(k, cs0, 0);
    __syncthreads();
    int cur = k & 1;
    #pragma unroll
    for (int kk = 0; kk < 4; ++kk) {
      bfrag8 B0 = *(const bfrag8*)&lbuf[cur][0][lp][kk * 4 + g][0];
      bfrag8 B1 = *(const bfrag8*)&lbuf[cur][1][lp][kk * 4 + g][0];
      #pragma unroll
      for (int m = 0; m < 2; ++m) {
        bfrag8 af = wp[((size_t)((k * 8 + mtg0 + m) * 4 + kk)) * 64 + lane];
        acc[m][0] = __builtin_amdgcn_mfma_f32_16x16x32_bf16(af, B0, acc[m][0], 0, 0, 0);
        acc[m][1] = __builtin_amdgcn_mfma_f32_16x16x32_bf16(af, B1, acc[m][1], 0, 0, 0);
      }
    }
  }

  // epilogue: bias + store + GN partials. D: lane l reg r -> oc_local=(l>>4)*4+r, pix=l&15
  float lsum = 0.f, lsq = 0.f;
  #pragma unroll
  for (int m = 0; m < 2; ++m) {
    int oc = (mtg0 + m) * 16 + g * 4;
    float4 bias = *(const float4*)(de_b + oc);
    #pragma unroll
    for (int n = 0; n < 2; ++n) {
      int pix = pixbase + n * 16 + lp;
      f32x4 a = acc[m][n];
      float4 v = make_float4(a[0] + bias.x, a[1] + bias.y, a[2] + bias.z, a[3] + bias.w);
      *(float4*)(d + (size_t)pix * 128 + oc) = v;
      lsum += v.x + v.y + v.z + v.w;
      lsq  += v.x * v.x + v.y * v.y + v.z * v.z + v.w * v.w;
    }
  }
  __syncthreads();
  r1[tid] = lsum; r2[tid] = lsq;
  __syncthreads();
  for (int st = 128; st > 0; st >>= 1) {
    if (tid < st) { r1[tid] += r1[tid + st]; r2[tid] += r2[tid + st]; }
    __syncthreads();
  }
  if (tid == 0) {
    int b = pixbase / HW_;
    atomicAdd(&gst[b * 2],     r1[0]);
    atomicAdd(&gst[b * 2 + 1], r2[0]);
  }
}

// ---------------- final: GN (inline finalize) + sigmoid gate + shortcut ----
// shortcut read from bf16 nsamp (relu-normalized s) -> half the read bytes.
__global__ __launch_bounds__(256) void k_final(
    const float* __restrict__ d, const short* __restrict__ nsamp,
    const float* __restrict__ gst, const float* __restrict__ gn_w,
    const float* __restrict__ gn_b, float* __restrict__ out) {
  __shared__ float t[128 * 33];
  int tid = threadIdx.x;
  int pixbase = blockIdx.x * 32;
  int b = pixbase / HW_;
  int hw0 = pixbase % HW_;
  const float invN = 1.f / (float)BATCH_STRIDE;
  float gm = gst[2 * b] * invN;
  float gr = rsqrtf(gst[2 * b + 1] * invN - gm * gm + 1e-5f);

  int px0 = tid >> 3;
  int c0  = (tid & 7) * 16;
  const float* dp = d + ((size_t)(pixbase + px0)) * 128;
  const short* np = nsamp + ((size_t)(pixbase + px0)) * 128 + c0;
  bfrag8 sv0 = *(const bfrag8*)np;
  bfrag8 sv1 = *(const bfrag8*)(np + 8);
  #pragma unroll
  for (int q = 0; q < 4; ++q) {
    int c = c0 + q * 4;
    float4 dv = *(const float4*)(dp + c);
    float4 w4 = *(const float4*)(gn_w + c);
    float4 b4 = *(const float4*)(gn_b + c);
    #pragma unroll
    for (int e = 0; e < 4; ++e) {
      int idx = q * 4 + e;
      float svn = bf2f(idx < 8 ? sv0[idx & 7] : sv1[idx & 7]);
      float dvx = e == 0 ? dv.x : (e == 1 ? dv.y : (e == 2 ? dv.z : dv.w));
      float wx  = e == 0 ? w4.x : (e == 1 ? w4.y : (e == 2 ? w4.z : w4.w));
      float bx  = e == 0 ? b4.x : (e == 1 ? b4.y : (e == 2 ? b4.z : b4.w));
      float dn = (dvx - gm) * gr * wx + bx;
      float gg = 1.f / (1.f + expf(-dn));
      t[(c + e) * 33 + px0] = svn * (1.f + gg);
    }
  }
  __syncthreads();
  if (tid < 128) {
    float* op = out + (size_t)(b * 128 + tid) * HW_ + hw0;
    #pragma unroll
    for (int p4 = 0; p4 < 8; ++p4) {
      float4 v = make_float4(t[tid * 33 + p4 * 4], t[tid * 33 + p4 * 4 + 1],
                             t[tid * 33 + p4 * 4 + 2], t[tid * 33 + p4 * 4 + 3]);
      *(float4*)(op + p4 * 4) = v;
    }
  }
}

extern "C" void kernel_launch(void* const* d_in, const int* in_sizes, int n_in,
                              void* d_out, int out_size, void* d_ws, size_t ws_size,
                              hipStream_t stream) {
  (void)in_sizes; (void)n_in; (void)out_size; (void)ws_size;
  const float* x     = (const float*)d_in[0];
  const float* dw_w  = (const float*)d_in[1];
  const float* dw_b  = (const float*)d_in[2];
  const float* pw_w  = (const float*)d_in[3];
  const float* pw_b  = (const float*)d_in[4];
  const float* off_w = (const float*)d_in[5];
  const float* off_b = (const float*)d_in[6];
  const float* de_w  = (const float*)d_in[7];
  const float* de_b  = (const float*)d_in[8];
  const float* gn_w  = (const float*)d_in[9];
  const float* gn_b  = (const float*)d_in[10];
  float* out = (float*)d_out;

  float* ws   = (float*)d_ws;
  float* h1   = ws;                 // NCHW depthwise out; reused as deform out d (BHWC)
  float* s    = h1 + BHWC;          // BHWC raw pw output
  float* off  = s + BHWC;           // [18][NPIX] offsets (oc-major)
  short* wtb  = (short*)(off + NPIX * 18);  // bf16 A-frag de_w (147456 shorts)
  short* wob  = wtb + 147456;       // bf16 A-frag off_w (36864 shorts)
  short* pwb  = wob + 36864;        // bf16 A-frag pw_w (16384 shorts)
  float* ist  = (float*)(pwb + 16384);  // [B][C][2] sum,sumsq
  float* gst  = ist + 1024;         // [B][2]
  short* nsamp = (short*)(gst + 8); // bf16 normalized s, pixel-major (NPIX*128)

  hipMemsetAsync(ist, 0, (1024 + 8) * sizeof(float), stream);

  k_transpose_w<<<576, 256, 0, stream>>>(de_w, off_w, pw_w, wtb, wob, pwb);
  k_dw<<<BHWC / 256, 256, 0, stream>>>(x, dw_w, dw_b, h1);
  k_pw<<<NPIX / 64, 256, 0, stream>>>(h1, pwb, pw_b, s, ist);
  k_norm<<<NPIX * 16 / 256, 256, 0, stream>>>(s, ist, nsamp);
  k_offgemm<<<NPIX / 128, 256, 0, stream>>>(nsamp, wob, off_b, off);
  k_deform_f<<<NPIX / 32, 256, 0, stream>>>(nsamp, off, wtb, de_b, h1, gst);
  k_final<<<NPIX / 32, 256, 0, stream>>>(h1, nsamp, gst, gn_w, gn_b, out);
}

// Round 16
// 138.914 us; speedup vs baseline: 1.6251x; 1.1901x over previous
//
#include <hip/hip_runtime.h>
#include <hip/hip_bf16.h>
#include <math.h>

#define B_    4
#define C_    128
#define H_    96
#define W_    96
#define HW_   9216          // H*W
#define NPIX  36864         // B*HW
#define BHWC  4718592       // B*HW*C
#define BATCH_STRIDE 1179648 // HW*C

typedef __attribute__((ext_vector_type(8))) short bfrag8;
typedef __attribute__((ext_vector_type(4))) float f32x4;

static __device__ __forceinline__ short f2bf(float f) {
  __hip_bfloat16 h = __float2bfloat16(f);
  short s;
  __builtin_memcpy(&s, &h, 2);
  return s;
}
static __device__ __forceinline__ float bf2f(short s) {
  unsigned u = ((unsigned)(unsigned short)s) << 16;
  float f;
  __builtin_memcpy(&f, &u, 4);
  return f;
}
// pack two f32 -> two bf16 (RNE) in one instruction
static __device__ __forceinline__ unsigned cvtpk(float lo, float hi) {
  unsigned r;
  asm("v_cvt_pk_bf16_f32 %0, %1, %2" : "=v"(r) : "v"(lo), "v"(hi));
  return r;
}

// ---------------- weight transposes ----------------
// wtb: bf16 A-frag order [k][mt(8)][kk(4)][lane(64)][j(8)] for de_w (147456)
// wob: bf16 A-frag order [k][mt(2)][kk(4)][lane(64)][j(8)] for off_w (36864)
// pwb: bf16 A-frag order [mt(8)][kk(4)][lane(64)][j(8)] for pw_w (16384)
__global__ void k_transpose_w(const float* __restrict__ de_w,
                              const float* __restrict__ off_w,
                              const float* __restrict__ pw_w,
                              short* __restrict__ wtb, short* __restrict__ wob,
                              short* __restrict__ pwb) {
  int i = blockIdx.x * 256 + threadIdx.x;
  if (i < 147456) {
    int j  = i & 7;
    int l  = (i >> 3) & 63;
    int kk = (i >> 9) & 3;
    int mt = (i >> 11) & 7;
    int k  = i >> 14;
    int oc = mt * 16 + (l & 15);
    int c  = kk * 32 + ((l >> 4) << 3) + j;
    wtb[i] = f2bf(de_w[(oc * 128 + c) * 9 + k]);
  }
  if (i < 36864) {
    int j  = i & 7;
    int l  = (i >> 3) & 63;
    int kk = (i >> 9) & 3;
    int mt = (i >> 11) & 1;
    int k  = i >> 12;
    int oc = mt * 16 + (l & 15);
    int c  = kk * 32 + ((l >> 4) << 3) + j;
    wob[i] = (oc < 18) ? f2bf(off_w[(oc * 128 + c) * 9 + k]) : (short)0;
  }
  if (i < 16384) {
    int j  = i & 7;
    int l  = (i >> 3) & 63;
    int kk = (i >> 9) & 3;
    int mt = i >> 11;
    int oc = mt * 16 + (l & 15);
    int c  = kk * 32 + ((l >> 4) << 3) + j;
    pwb[i] = f2bf(pw_w[oc * 128 + c]);
  }
}

// ------ fused depthwise+pointwise MFMA + IN-stats : x -> sbf(bf16), ist ------
// block = 64 pix x 128 oc, 4 waves; grid NPIX/64 = 576.
// Stage: thread (pixloc, cq) computes dw 3x3 on the fly for its 32 channels
// (per-tap offset/valid computed ONCE, reused across channels; dw weights
// wave-uniform -> scalar loads; window loads coalesced over 64 contig pixels),
// cvt_pk -> bf16 B-frags in LDS. MFMA phase unchanged. Epilogue: bf16 s +
// fp32 IN-stats partials (shfl_xor + LDS + 1 atomic/channel).
__global__ __launch_bounds__(256) void k_pw(
    const float* __restrict__ x, const float* __restrict__ dw_w,
    const float* __restrict__ dw_b, const short* __restrict__ pwb,
    const float* __restrict__ pw_b, short* __restrict__ sbf,
    float* __restrict__ ist) {
  __shared__ short lb[4][4][64][8];   // [pb][kk][lane][j], 16 KB
  __shared__ float ps[4][128], pq2[4][128];  // 4 KB stats partials
  int tid = threadIdx.x;
  int pixbase = blockIdx.x * 64;
  int b = pixbase / HW_;
  int hw0 = pixbase % HW_;

  int pixloc = tid & 63, cq = tid >> 6;
  {
    int hw = hw0 + pixloc;
    int y = hw / 96, xx = hw % 96;
    const float* xb = x + (size_t)b * 128 * HW_;
    int toff[9];
    float tmask[9];
    #pragma unroll
    for (int dy = 0; dy < 3; ++dy) {
      #pragma unroll
      for (int dx = 0; dx < 3; ++dx) {
        int sy = y + dy - 1, sx = xx + dx - 1;
        bool vld = ((unsigned)sy < 96u) && ((unsigned)sx < 96u);
        int syc = min(max(sy, 0), 95), sxc = min(max(sx, 0), 95);
        toff[dy * 3 + dx] = syc * 96 + sxc;
        tmask[dy * 3 + dx] = vld ? 1.f : 0.f;
      }
    }
    #pragma unroll
    for (int it = 0; it < 4; ++it) {
      int c8 = cq * 4 + it;
      int c0 = c8 * 8;
      float v[8];
      #pragma unroll
      for (int j = 0; j < 8; ++j) {
        int c = c0 + j;
        const float* xp = xb + (size_t)c * HW_;
        const float* wp = dw_w + c * 9;
        float a = dw_b[c];
        #pragma unroll
        for (int t9 = 0; t9 < 9; ++t9)
          a = fmaf(xp[toff[t9]] * tmask[t9], wp[t9], a);
        v[j] = a;
      }
      unsigned o0 = cvtpk(v[0], v[1]), o1 = cvtpk(v[2], v[3]);
      unsigned o2 = cvtpk(v[4], v[5]), o3 = cvtpk(v[6], v[7]);
      *(uint4*)&lb[pixloc >> 4][c8 >> 2][(c8 & 3) * 16 + (pixloc & 15)][0] =
          make_uint4(o0, o1, o2, o3);
    }
  }
  __syncthreads();

  int lane = tid & 63, wv = tid >> 6;
  int lp = lane & 15, g = lane >> 4;
  const bfrag8* wp8 = (const bfrag8*)pwb;

  f32x4 acc[8];
  #pragma unroll
  for (int m = 0; m < 8; ++m) acc[m] = (f32x4){0.f, 0.f, 0.f, 0.f};

  #pragma unroll
  for (int kk = 0; kk < 4; ++kk) {
    bfrag8 Bf = *(const bfrag8*)&lb[wv][kk][lane][0];
    #pragma unroll
    for (int m = 0; m < 8; ++m) {
      bfrag8 af = wp8[((size_t)(m * 4 + kk)) * 64 + lane];
      acc[m] = __builtin_amdgcn_mfma_f32_16x16x32_bf16(af, Bf, acc[m], 0, 0, 0);
    }
  }

  int pix = pixbase + wv * 16 + lp;
  #pragma unroll
  for (int m = 0; m < 8; ++m) {
    int oc = m * 16 + g * 4;
    float4 bias = *(const float4*)(pw_b + oc);
    f32x4 a = acc[m];
    float4 v = make_float4(a[0] + bias.x, a[1] + bias.y, a[2] + bias.z, a[3] + bias.w);
    *(uint2*)(sbf + (size_t)pix * 128 + oc) = make_uint2(cvtpk(v.x, v.y), cvtpk(v.z, v.w));
    // per-channel partial sums over the wave's 16 pixels (lp lanes), fp32
    float t0 = v.x, t1 = v.y, t2 = v.z, t3 = v.w;
    float u0 = v.x * v.x, u1 = v.y * v.y, u2 = v.z * v.z, u3 = v.w * v.w;
    #pragma unroll
    for (int mask = 1; mask <= 8; mask <<= 1) {
      t0 += __shfl_xor(t0, mask); t1 += __shfl_xor(t1, mask);
      t2 += __shfl_xor(t2, mask); t3 += __shfl_xor(t3, mask);
      u0 += __shfl_xor(u0, mask); u1 += __shfl_xor(u1, mask);
      u2 += __shfl_xor(u2, mask); u3 += __shfl_xor(u3, mask);
    }
    if (lp == 0) {
      ps[wv][oc + 0] = t0; ps[wv][oc + 1] = t1; ps[wv][oc + 2] = t2; ps[wv][oc + 3] = t3;
      pq2[wv][oc + 0] = u0; pq2[wv][oc + 1] = u1; pq2[wv][oc + 2] = u2; pq2[wv][oc + 3] = u3;
    }
  }
  __syncthreads();
  if (tid < 128) {
    float su = ps[0][tid] + ps[1][tid] + ps[2][tid] + ps[3][tid];
    float sq = pq2[0][tid] + pq2[1][tid] + pq2[2][tid] + pq2[3][tid];
    atomicAdd(&ist[(size_t)(b * 128 + tid) * 2],     su);
    atomicAdd(&ist[(size_t)(b * 128 + tid) * 2 + 1], sq);
  }
}

// ---------------- normalize sbf(bf16) -> bf16 pixel-major nsamp ------------
__global__ __launch_bounds__(256) void k_norm(
    const short* __restrict__ sbf, const float* __restrict__ ist,
    short* __restrict__ nsamp) {
  int t = blockIdx.x * 256 + threadIdx.x;   // t < NPIX*16
  int pix = t >> 4; int c0 = (t & 15) * 8;
  int b = pix / HW_;
  bfrag8 sv = *(const bfrag8*)(sbf + (size_t)pix * 128 + c0);
  bfrag8 o;
  #pragma unroll
  for (int j = 0; j < 8; ++j) {
    size_t ci = (size_t)(b * 128 + c0 + j) * 2;
    float mean = ist[ci] * (1.f / 9216.f);
    float var  = ist[ci + 1] * (1.f / 9216.f) - mean * mean;
    float rs = rsqrtf(var + 1e-5f);
    o[j] = f2bf(fmaxf((bf2f(sv[j]) - mean) * rs, 0.f));
  }
  *(bfrag8*)(nsamp + (size_t)pix * 128 + c0) = o;
}

// ---------------- offset conv as MFMA GEMM with shifted fragments ----------
__global__ __launch_bounds__(256) void k_offgemm(
    const short* __restrict__ nsamp, const short* __restrict__ wob,
    const float* __restrict__ off_b, float* __restrict__ off) {
  int tid = threadIdx.x;
  int lane = tid & 63, wv = tid >> 6;
  int p0 = blockIdx.x * 128 + wv * 32;
  int lp = lane & 15, g = lane >> 4;
  const bfrag8* np = (const bfrag8*)nsamp;
  const bfrag8* wp = (const bfrag8*)wob;

  f32x4 acc[2][2];
  #pragma unroll
  for (int m = 0; m < 2; ++m)
    #pragma unroll
    for (int n = 0; n < 2; ++n) acc[m][n] = (f32x4){0.f, 0.f, 0.f, 0.f};

  int pn0 = p0 + lp, pn1 = p0 + 16 + lp;
  int x0_ = pn0 % 96, y0_ = (pn0 % HW_) / 96;
  int x1_ = pn1 % 96, y1_ = (pn1 % HW_) / 96;
  const bfrag8 zf = {0, 0, 0, 0, 0, 0, 0, 0};

  for (int k = 0; k < 9; ++k) {
    int dy = k / 3 - 1, dx = k % 3 - 1;
    int sh = dy * 96 + dx;
    bool v0 = ((unsigned)(x0_ + dx) < 96u) && ((unsigned)(y0_ + dy) < 96u);
    bool v1 = ((unsigned)(x1_ + dx) < 96u) && ((unsigned)(y1_ + dy) < 96u);
    int q0 = min(max(pn0 + sh, 0), NPIX - 1);
    int q1 = min(max(pn1 + sh, 0), NPIX - 1);
    size_t a0 = (size_t)q0 * 16 + g;
    size_t a1 = (size_t)q1 * 16 + g;
    #pragma unroll
    for (int kk = 0; kk < 4; ++kk) {
      bfrag8 B0 = np[a0 + kk * 4]; B0 = v0 ? B0 : zf;
      bfrag8 B1 = np[a1 + kk * 4]; B1 = v1 ? B1 : zf;
      bfrag8 A0 = wp[((size_t)(k * 2 + 0) * 4 + kk) * 64 + lane];
      bfrag8 A1 = wp[((size_t)(k * 2 + 1) * 4 + kk) * 64 + lane];
      acc[0][0] = __builtin_amdgcn_mfma_f32_16x16x32_bf16(A0, B0, acc[0][0], 0, 0, 0);
      acc[0][1] = __builtin_amdgcn_mfma_f32_16x16x32_bf16(A0, B1, acc[0][1], 0, 0, 0);
      acc[1][0] = __builtin_amdgcn_mfma_f32_16x16x32_bf16(A1, B0, acc[1][0], 0, 0, 0);
      acc[1][1] = __builtin_amdgcn_mfma_f32_16x16x32_bf16(A1, B1, acc[1][1], 0, 0, 0);
    }
  }

  #pragma unroll
  for (int mt = 0; mt < 2; ++mt) {
    #pragma unroll
    for (int r = 0; r < 4; ++r) {
      int oc = mt * 16 + g * 4 + r;
      if (oc < 18) {
        float bb = off_b[oc];
        off[(size_t)oc * NPIX + p0 + lp]      = acc[mt][0][r] + bb;
        off[(size_t)oc * NPIX + p0 + 16 + lp] = acc[mt][1][r] + bb;
      }
    }
  }
}

// ---------------- fused deform: T14 async ISSUE/FINISH + MFMA + GN stats ----
// block = 32 pix x 128 oc, 4 waves; grid 1152 (= 8*144, XCD-swizzled).
// d output is bf16 (GN partials still fp32).
__global__ __launch_bounds__(256) void k_deform_f(
    const short* __restrict__ nsamp, const float* __restrict__ off,
    const short* __restrict__ wtb, const float* __restrict__ de_b,
    short* __restrict__ d, float* __restrict__ gst) {
  __shared__ short lbuf[2][2][16][17][8];  // 17.4 KB
  __shared__ float offl[18][32];           // 2.3 KB
  __shared__ float r1[256], r2[256];
  int tid = threadIdx.x;
  int bid = blockIdx.x;
  int wg = (bid & 7) * 144 + (bid >> 3);   // bijective for 1152
  int pixbase = wg * 32;

  int lane = tid & 63, wv = tid >> 6;
  int lp = lane & 15, g = lane >> 4;
  int pq = lane >> 4, ch = lane & 15;      // sampling role

  // stage offsets for this block's 32 pixels: 18 x 32 floats
  #pragma unroll
  for (int t = 0; t < 3; ++t) {
    int i = t * 256 + tid;
    if (i < 576)
      offl[i >> 5][i & 31] = off[(size_t)(i >> 5) * NPIX + pixbase + (i & 31)];
  }
  __syncthreads();

  // per-q pixel constants (sampling role)
  int lpixA[2], ysA[2], xsA[2], qbA[2];
  #pragma unroll
  for (int q = 0; q < 2; ++q) {
    int lpix = wv * 8 + q * 4 + pq;
    int pix = pixbase + lpix;
    int hw = pix % HW_;
    lpixA[q] = lpix;
    ysA[q] = hw / 96;
    xsA[q] = hw % 96;
    qbA[q] = (pix / HW_) * HW_;
  }

  // mfma role
  int mtg0 = wv * 2;
  const bfrag8* wp = (const bfrag8*)wtb;

  f32x4 acc[2][2];
  #pragma unroll
  for (int m = 0; m < 2; ++m)
    #pragma unroll
    for (int n = 0; n < 2; ++n) acc[m][n] = (f32x4){0.f, 0.f, 0.f, 0.f};

  bfrag8 cs0[2][4], cs1[2][4];   // two corner-register sets

  auto ISSUE = [&](int k, bfrag8 (&cs)[2][4]) {
    #pragma unroll
    for (int q = 0; q < 2; ++q) {
      float dy = offl[2 * k][lpixA[q]];
      float dx = offl[2 * k + 1][lpixA[q]];
      float py = (float)ysA[q] + (float)(k / 3 - 1) + dy;
      float px = (float)xsA[q] + (float)(k % 3 - 1) + dx;
      int y0 = (int)floorf(py), x0 = (int)floorf(px);
      int yc0 = min(max(y0, 0), 95), yc1 = min(max(y0 + 1, 0), 95);
      int xc0 = min(max(x0, 0), 95), xc1 = min(max(x0 + 1, 0), 95);
      const short* base = nsamp + (size_t)ch * 8;
      cs[q][0] = *(const bfrag8*)(base + (size_t)(qbA[q] + yc0 * 96 + xc0) * 128);
      cs[q][1] = *(const bfrag8*)(base + (size_t)(qbA[q] + yc0 * 96 + xc1) * 128);
      cs[q][2] = *(const bfrag8*)(base + (size_t)(qbA[q] + yc1 * 96 + xc0) * 128);
      cs[q][3] = *(const bfrag8*)(base + (size_t)(qbA[q] + yc1 * 96 + xc1) * 128);
    }
  };

  auto FINISH = [&](int k, bfrag8 (&cs)[2][4], int buf) {
    #pragma unroll
    for (int q = 0; q < 2; ++q) {
      float dy = offl[2 * k][lpixA[q]];
      float dx = offl[2 * k + 1][lpixA[q]];
      float py = (float)ysA[q] + (float)(k / 3 - 1) + dy;
      float px = (float)xsA[q] + (float)(k % 3 - 1) + dx;
      float y0f = floorf(py), x0f = floorf(px);
      float ly = py - y0f, lx = px - x0f;
      int y0 = (int)y0f, x0 = (int)x0f;
      bool vy0 = (y0 >= 0) && (y0 < 96), vy1 = (y0 + 1 >= 0) && (y0 + 1 < 96);
      bool vx0 = (x0 >= 0) && (x0 < 96), vx1 = (x0 + 1 >= 0) && (x0 + 1 < 96);
      float w00 = (vy0 && vx0) ? (1.f - ly) * (1.f - lx) : 0.f;
      float w01 = (vy0 && vx1) ? (1.f - ly) * lx : 0.f;
      float w10 = (vy1 && vx0) ? ly * (1.f - lx) : 0.f;
      float w11 = (vy1 && vx1) ? ly * lx : 0.f;
      float v[8];
      #pragma unroll
      for (int j = 0; j < 8; ++j) {
        v[j] = bf2f(cs[q][0][j]) * w00 + bf2f(cs[q][1][j]) * w01
             + bf2f(cs[q][2][j]) * w10 + bf2f(cs[q][3][j]) * w11;
      }
      unsigned o0 = cvtpk(v[0], v[1]), o1 = cvtpk(v[2], v[3]);
      unsigned o2 = cvtpk(v[4], v[5]), o3 = cvtpk(v[6], v[7]);
      int lpix = lpixA[q];
      *(uint4*)&lbuf[buf][lpix >> 4][lpix & 15][ch][0] = make_uint4(o0, o1, o2, o3);
    }
  };

  ISSUE(0, cs0);
  #pragma unroll
  for (int k = 0; k < 9; ++k) {
    if (k < 8) {
      if ((k + 1) & 1) ISSUE(k + 1, cs1);
      else             ISSUE(k + 1, cs0);
    }
    if (k & 1) FINISH(k, cs1, 1);
    else       FINISH(k, cs0, 0);
    __syncthreads();
    int cur = k & 1;
    #pragma unroll
    for (int kk = 0; kk < 4; ++kk) {
      bfrag8 B0 = *(const bfrag8*)&lbuf[cur][0][lp][kk * 4 + g][0];
      bfrag8 B1 = *(const bfrag8*)&lbuf[cur][1][lp][kk * 4 + g][0];
      #pragma unroll
      for (int m = 0; m < 2; ++m) {
        bfrag8 af = wp[((size_t)((k * 8 + mtg0 + m) * 4 + kk)) * 64 + lane];
        acc[m][0] = __builtin_amdgcn_mfma_f32_16x16x32_bf16(af, B0, acc[m][0], 0, 0, 0);
        acc[m][1] = __builtin_amdgcn_mfma_f32_16x16x32_bf16(af, B1, acc[m][1], 0, 0, 0);
      }
    }
  }

  // epilogue: bias + bf16 store + GN partials (fp32).
  float lsum = 0.f, lsq = 0.f;
  #pragma unroll
  for (int m = 0; m < 2; ++m) {
    int oc = (mtg0 + m) * 16 + g * 4;
    float4 bias = *(const float4*)(de_b + oc);
    #pragma unroll
    for (int n = 0; n < 2; ++n) {
      int pix = pixbase + n * 16 + lp;
      f32x4 a = acc[m][n];
      float4 v = make_float4(a[0] + bias.x, a[1] + bias.y, a[2] + bias.z, a[3] + bias.w);
      *(uint2*)(d + (size_t)pix * 128 + oc) = make_uint2(cvtpk(v.x, v.y), cvtpk(v.z, v.w));
      lsum += v.x + v.y + v.z + v.w;
      lsq  += v.x * v.x + v.y * v.y + v.z * v.z + v.w * v.w;
    }
  }
  __syncthreads();
  r1[tid] = lsum; r2[tid] = lsq;
  __syncthreads();
  for (int st = 128; st > 0; st >>= 1) {
    if (tid < st) { r1[tid] += r1[tid + st]; r2[tid] += r2[tid + st]; }
    __syncthreads();
  }
  if (tid == 0) {
    int b = pixbase / HW_;
    atomicAdd(&gst[b * 2],     r1[0]);
    atomicAdd(&gst[b * 2 + 1], r2[0]);
  }
}

// ---------------- final: GN (inline finalize) + sigmoid gate + shortcut ----
// d and shortcut both read as bf16.
__global__ __launch_bounds__(256) void k_final(
    const short* __restrict__ d, const short* __restrict__ nsamp,
    const float* __restrict__ gst, const float* __restrict__ gn_w,
    const float* __restrict__ gn_b, float* __restrict__ out) {
  __shared__ float t[128 * 33];
  int tid = threadIdx.x;
  int pixbase = blockIdx.x * 32;
  int b = pixbase / HW_;
  int hw0 = pixbase % HW_;
  const float invN = 1.f / (float)BATCH_STRIDE;
  float gm = gst[2 * b] * invN;
  float gr = rsqrtf(gst[2 * b + 1] * invN - gm * gm + 1e-5f);

  int px0 = tid >> 3;
  int c0  = (tid & 7) * 16;
  const short* dp = d + ((size_t)(pixbase + px0)) * 128 + c0;
  const short* np = nsamp + ((size_t)(pixbase + px0)) * 128 + c0;
  bfrag8 dv0 = *(const bfrag8*)dp;
  bfrag8 dv1 = *(const bfrag8*)(dp + 8);
  bfrag8 sv0 = *(const bfrag8*)np;
  bfrag8 sv1 = *(const bfrag8*)(np + 8);
  #pragma unroll
  for (int q = 0; q < 4; ++q) {
    int c = c0 + q * 4;
    float4 w4 = *(const float4*)(gn_w + c);
    float4 b4 = *(const float4*)(gn_b + c);
    #pragma unroll
    for (int e = 0; e < 4; ++e) {
      int idx = q * 4 + e;
      float dvx = bf2f(idx < 8 ? dv0[idx & 7] : dv1[idx & 7]);
      float svn = bf2f(idx < 8 ? sv0[idx & 7] : sv1[idx & 7]);
      float wx  = e == 0 ? w4.x : (e == 1 ? w4.y : (e == 2 ? w4.z : w4.w));
      float bx  = e == 0 ? b4.x : (e == 1 ? b4.y : (e == 2 ? b4.z : b4.w));
      float dn = (dvx - gm) * gr * wx + bx;
      float gg = 1.f / (1.f + expf(-dn));
      t[(c + e) * 33 + px0] = svn * (1.f + gg);
    }
  }
  __syncthreads();
  if (tid < 128) {
    float* op = out + (size_t)(b * 128 + tid) * HW_ + hw0;
    #pragma unroll
    for (int p4 = 0; p4 < 8; ++p4) {
      float4 v = make_float4(t[tid * 33 + p4 * 4], t[tid * 33 + p4 * 4 + 1],
                             t[tid * 33 + p4 * 4 + 2], t[tid * 33 + p4 * 4 + 3]);
      *(float4*)(op + p4 * 4) = v;
    }
  }
}

extern "C" void kernel_launch(void* const* d_in, const int* in_sizes, int n_in,
                              void* d_out, int out_size, void* d_ws, size_t ws_size,
                              hipStream_t stream) {
  (void)in_sizes; (void)n_in; (void)out_size; (void)ws_size;
  const float* x     = (const float*)d_in[0];
  const float* dw_w  = (const float*)d_in[1];
  const float* dw_b  = (const float*)d_in[2];
  const float* pw_w  = (const float*)d_in[3];
  const float* pw_b  = (const float*)d_in[4];
  const float* off_w = (const float*)d_in[5];
  const float* off_b = (const float*)d_in[6];
  const float* de_w  = (const float*)d_in[7];
  const float* de_b  = (const float*)d_in[8];
  const float* gn_w  = (const float*)d_in[9];
  const float* gn_b  = (const float*)d_in[10];
  float* out = (float*)d_out;

  float* ws   = (float*)d_ws;
  float* off  = ws;                        // [18][NPIX] offsets (oc-major)
  short* wtb  = (short*)(off + NPIX * 18); // bf16 A-frag de_w (147456 shorts)
  short* wob  = wtb + 147456;              // bf16 A-frag off_w (36864 shorts)
  short* pwb  = wob + 36864;               // bf16 A-frag pw_w (16384 shorts)
  float* ist  = (float*)(pwb + 16384);     // [B][C][2] sum,sumsq
  float* gst  = ist + 1024;                // [B][2]
  short* sbf  = (short*)(gst + 8);         // bf16 dw+pw out, pixel-major (NPIX*128)
  short* dbf  = sbf + (size_t)NPIX * 128;  // bf16 deform out, pixel-major
  short* nsamp = dbf + (size_t)NPIX * 128; // bf16 normalized, pixel-major

  hipMemsetAsync(ist, 0, (1024 + 8) * sizeof(float), stream);

  k_transpose_w<<<576, 256, 0, stream>>>(de_w, off_w, pw_w, wtb, wob, pwb);
  k_pw<<<NPIX / 64, 256, 0, stream>>>(x, dw_w, dw_b, pwb, pw_b, sbf, ist);
  k_norm<<<NPIX * 16 / 256, 256, 0, stream>>>(sbf, ist, nsamp);
  k_offgemm<<<NPIX / 128, 256, 0, stream>>>(nsamp, wob, off_b, off);
  k_deform_f<<<NPIX / 32, 256, 0, stream>>>(nsamp, off, wtb, de_b, dbf, gst);
  k_final<<<NPIX / 32, 256, 0, stream>>>(dbf, nsamp, gst, gn_w, gn_b, out);
}